// Round 1
// baseline (651.579 us; speedup 1.0000x reference)
//
#include <hip/hip_runtime.h>
#include <hip/hip_bf16.h>

#define NB 8
#define CC 64
#define HWP 65536          // H*W

typedef __attribute__((ext_vector_type(8))) short short8;
typedef __attribute__((ext_vector_type(4))) float f32x4;

__device__ __forceinline__ short f2bf(float f) {
  union { float f; unsigned u; } v; v.f = f;
  return (short)((v.u + 0x7FFF + ((v.u >> 16) & 1)) >> 16);
}
__device__ __forceinline__ float bf2f(unsigned short u) {
  union { unsigned u; float f; } v; v.u = ((unsigned)u) << 16; return v.f;
}

// ---------------- LN stats: one block per (n,c) plane --------------------
__global__ __launch_bounds__(256) void ln_stats_kernel(
    const float* __restrict__ x, const float* __restrict__ lw,
    const float* __restrict__ lb, float* __restrict__ a, float* __restrict__ b) {
  int plane = blockIdx.x;            // n*64 + c
  int c = plane & 63;
  const float4* p4 = (const float4*)(x + (size_t)plane * HWP);
  float s = 0.f, s2 = 0.f;
  for (int i = threadIdx.x; i < HWP / 4; i += 256) {
    float4 v = p4[i];
    s  += v.x + v.y + v.z + v.w;
    s2 += v.x * v.x + v.y * v.y + v.z * v.z + v.w * v.w;
  }
  for (int off = 32; off; off >>= 1) {
    s  += __shfl_down(s, off);
    s2 += __shfl_down(s2, off);
  }
  __shared__ float ls[4], ls2[4];
  int wid = threadIdx.x >> 6, lid = threadIdx.x & 63;
  if (lid == 0) { ls[wid] = s; ls2[wid] = s2; }
  __syncthreads();
  if (threadIdx.x == 0) {
    float S  = ls[0] + ls[1] + ls[2] + ls[3];
    float S2 = ls2[0] + ls2[1] + ls2[2] + ls2[3];
    float mean = S * (1.f / (float)HWP);
    float var  = S2 * (1.f / (float)HWP) - mean * mean;
    float rstd = rsqrtf(var + 1e-6f);
    float av = rstd * lw[c];
    a[plane] = av;
    b[plane] = lb[c] - mean * av;
  }
}

// -------- fold LN into pw weights -----------------------------------------
__global__ void fold_kernel(const float* __restrict__ w, const float* __restrict__ pb,
                            const float* __restrict__ a, const float* __restrict__ b,
                            float* __restrict__ wf, float* __restrict__ cf, int O) {
  int idx = blockIdx.x * blockDim.x + threadIdx.x;   // n*O + o
  if (idx >= NB * O) return;
  int n = idx / O, o = idx - n * O;
  const float* an = a + n * 64;
  const float* bn = b + n * 64;
  const float* wo = w + o * 64;
  float* wfo = wf + (size_t)idx * 64;
  float cc = pb[o];
  for (int i = 0; i < 64; i++) { float wv = wo[i]; wfo[i] = wv * an[i]; cc += wv * bn[i]; }
  cf[idx] = cc;
}

// ---------------- pw1 via MFMA: z[n,o,p] = W1'[n] @ x[n] + c1', M=128 -----
__global__ __launch_bounds__(256, 2) void gemm_pw1_kernel(
    const float* __restrict__ x, const float* __restrict__ wf,
    const float* __restrict__ cf, unsigned short* __restrict__ z) {
  int n = blockIdx.y;
  int lane = threadIdx.x & 63, wid = threadIdx.x >> 6;
  int col = lane & 15, quad = lane >> 4;
  short8 a[8][2];
  const float* wfn = wf + (size_t)n * 128 * 64;
  #pragma unroll
  for (int mt = 0; mt < 8; mt++)
    #pragma unroll
    for (int ks = 0; ks < 2; ks++) {
      const float* wp = wfn + (mt * 16 + col) * 64 + ks * 32 + quad * 8;
      short8 v;
      #pragma unroll
      for (int j = 0; j < 8; j++) v[j] = f2bf(wp[j]);
      a[mt][ks] = v;
    }
  float cb[8][4];
  #pragma unroll
  for (int mt = 0; mt < 8; mt++)
    #pragma unroll
    for (int r = 0; r < 4; r++) cb[mt][r] = cf[n * 128 + mt * 16 + quad * 4 + r];
  const float* xn = x + (size_t)n * 64 * HWP;
  unsigned short* zn = z + (size_t)n * 128 * HWP;
  int pxbase = blockIdx.x * 512 + wid * 16 + col;
  for (int tile = 0; tile < 8; tile++) {
    int p = pxbase + tile * 64;
    short8 b[2];
    #pragma unroll
    for (int ks = 0; ks < 2; ks++)
      #pragma unroll
      for (int j = 0; j < 8; j++)
        b[ks][j] = f2bf(xn[(size_t)(ks * 32 + quad * 8 + j) * HWP + p]);
    f32x4 acc[8];
    #pragma unroll
    for (int mt = 0; mt < 8; mt++) {
      acc[mt] = (f32x4){0.f, 0.f, 0.f, 0.f};
      acc[mt] = __builtin_amdgcn_mfma_f32_16x16x32_bf16(a[mt][0], b[0], acc[mt], 0, 0, 0);
      acc[mt] = __builtin_amdgcn_mfma_f32_16x16x32_bf16(a[mt][1], b[1], acc[mt], 0, 0, 0);
    }
    #pragma unroll
    for (int mt = 0; mt < 8; mt++)
      #pragma unroll
      for (int r = 0; r < 4; r++)
        zn[(size_t)(mt * 16 + quad * 4 + r) * HWP + p] =
            (unsigned short)f2bf(acc[mt][r] + cb[mt][r]);
  }
}

// ---- depthwise 3x3 + SimpleGate + pool: row-streaming stencil ------------
// 1024 blocks: one block per (n,c,half-plane). 4 waves x 32-row bands.
// A wave covers a full 256-px row: 64 lanes x 4 px. Rolling 3-row register
// window per plane; halo pixels carried via shuffle at row-load time.
// Split from 512->1024 blocks: was 2 blocks/CU (2 waves/SIMD) — too little
// TLP to hide HBM latency for a pure streaming stencil.
__global__ __launch_bounds__(256) void dwgate_kernel(
    const unsigned short* __restrict__ z, const float* __restrict__ dww,
    const float* __restrict__ dwb, unsigned short* __restrict__ t,
    float* __restrict__ pooled2) {
  int blk = blockIdx.x;              // plane*2 + half
  int plane = blk >> 1, half = blk & 1;
  int n = plane >> 6, c = plane & 63;
  int lane = threadIdx.x & 63, wv = threadIdx.x >> 6;
  const unsigned short* z0 = z + ((size_t)n * 128 + c) * HWP;
  const unsigned short* z1 = z0 + (size_t)64 * HWP;
  unsigned short* tp = t + (size_t)plane * HWP;
  float w0[9], w1[9];
  #pragma unroll
  for (int k = 0; k < 9; k++) { w0[k] = dww[c * 9 + k]; w1[k] = dww[(c + 64) * 9 + k]; }
  float bias0 = dwb[c], bias1 = dwb[c + 64];
  int r0 = half * 128 + wv * 32;
  int colb = lane * 4;

  // row registers: [plane][window slot] -> 4 px + left/right halo
  float fa[3][4], la[3], ra[3];      // z0: slots prev, cur, next
  float fb[3][4], lb_[3], rb[3];     // z1

  auto loadrow = [&](const unsigned short* base, int h, float* f, float& l, float& r) {
    if ((unsigned)h < 256u) {
      ushort4 u = *(const ushort4*)(base + h * 256 + colb);
      f[0] = bf2f(u.x); f[1] = bf2f(u.y); f[2] = bf2f(u.z); f[3] = bf2f(u.w);
    } else {
      f[0] = f[1] = f[2] = f[3] = 0.f;
    }
    float ll = __shfl_up(f[3], 1);
    float rr = __shfl_down(f[0], 1);
    l = (lane == 0) ? 0.f : ll;
    r = (lane == 63) ? 0.f : rr;
  };

  loadrow(z0, r0 - 1, fa[0], la[0], ra[0]);
  loadrow(z1, r0 - 1, fb[0], lb_[0], rb[0]);
  loadrow(z0, r0,     fa[1], la[1], ra[1]);
  loadrow(z1, r0,     fb[1], lb_[1], rb[1]);

  float lsum = 0.f;
  #pragma unroll 2
  for (int h = r0; h < r0 + 32; h++) {
    loadrow(z0, h + 1, fa[2], la[2], ra[2]);
    loadrow(z1, h + 1, fb[2], lb_[2], rb[2]);
    float o0[4] = {bias0, bias0, bias0, bias0};
    float o1[4] = {bias1, bias1, bias1, bias1};
    #pragma unroll
    for (int rr_ = 0; rr_ < 3; rr_++) {
      float wl0 = w0[rr_ * 3], wc0 = w0[rr_ * 3 + 1], wr0 = w0[rr_ * 3 + 2];
      float wl1 = w1[rr_ * 3], wc1 = w1[rr_ * 3 + 1], wr1 = w1[rr_ * 3 + 2];
      const float* f0 = fa[rr_]; const float* f1 = fb[rr_];
      float l0 = la[rr_], r0h = ra[rr_], l1 = lb_[rr_], r1h = rb[rr_];
      o0[0] += wl0 * l0    + wc0 * f0[0] + wr0 * f0[1];
      o0[1] += wl0 * f0[0] + wc0 * f0[1] + wr0 * f0[2];
      o0[2] += wl0 * f0[1] + wc0 * f0[2] + wr0 * f0[3];
      o0[3] += wl0 * f0[2] + wc0 * f0[3] + wr0 * r0h;
      o1[0] += wl1 * l1    + wc1 * f1[0] + wr1 * f1[1];
      o1[1] += wl1 * f1[0] + wc1 * f1[1] + wr1 * f1[2];
      o1[2] += wl1 * f1[1] + wc1 * f1[2] + wr1 * f1[3];
      o1[3] += wl1 * f1[2] + wc1 * f1[3] + wr1 * r1h;
    }
    float g0 = o0[0] * o1[0], g1 = o0[1] * o1[1];
    float g2 = o0[2] * o1[2], g3 = o0[3] * o1[3];
    uint2 pk;
    pk.x = (unsigned)(unsigned short)f2bf(g0) | ((unsigned)(unsigned short)f2bf(g1) << 16);
    pk.y = (unsigned)(unsigned short)f2bf(g2) | ((unsigned)(unsigned short)f2bf(g3) << 16);
    *(uint2*)(tp + (size_t)h * 256 + colb) = pk;
    lsum += (g0 + g1) + (g2 + g3);
    // rotate window
    #pragma unroll
    for (int i = 0; i < 4; i++) { fa[0][i] = fa[1][i]; fa[1][i] = fa[2][i];
                                  fb[0][i] = fb[1][i]; fb[1][i] = fb[2][i]; }
    la[0] = la[1]; la[1] = la[2]; ra[0] = ra[1]; ra[1] = ra[2];
    lb_[0] = lb_[1]; lb_[1] = lb_[2]; rb[0] = rb[1]; rb[1] = rb[2];
  }
  for (int off = 32; off; off >>= 1) lsum += __shfl_down(lsum, off);
  __shared__ float ls[4];
  if (lane == 0) ls[wv] = lsum;
  __syncthreads();
  if (threadIdx.x == 0) pooled2[plane * 2 + half] = ls[0] + ls[1] + ls[2] + ls[3];
}

// ---------------- SCA ------------------------------------------------------
__global__ void sca_kernel(const float* __restrict__ pooled2, const float* __restrict__ sw,
                           const float* __restrict__ sb, float* __restrict__ sca) {
  int idx = blockIdx.x * blockDim.x + threadIdx.x;   // n*64 + o
  if (idx >= 512) return;
  int n = idx >> 6, o = idx & 63;
  float s = sb[o];
  const float* pm = pooled2 + n * 64 * 2;
  for (int i = 0; i < 64; i++)
    s += sw[o * 64 + i] * (pm[i * 2] + pm[i * 2 + 1]) * (1.f / 65536.f);
  sca[idx] = 1.f / (1.f + expf(-s));
}

// -------- fold SCA scale + beta1 into pw2 weights ---------------------------
__global__ void fold_pw2_kernel(const float* __restrict__ w, const float* __restrict__ pb,
                                const float* __restrict__ sca, const float* __restrict__ beta1,
                                float* __restrict__ wf, float* __restrict__ cf) {
  int idx = blockIdx.x * blockDim.x + threadIdx.x;   // n*64 + o
  if (idx >= 512) return;
  int n = idx >> 6, o = idx & 6 * 10 + 3;            // (kept below; see note)
  o = idx & 63;
  float bt = beta1[o];
  const float* sn = sca + n * 64;
  float* wfo = wf + (size_t)idx * 64;
  for (int i = 0; i < 64; i++) wfo[i] = bt * w[o * 64 + i] * sn[i];
  cf[idx] = bt * pb[o];
}

// ---------------- pw2 + residual via MFMA: x1 = x + W2' @ t + c2', M=64 ----
// Fused: per-plane LN2 partial stats (sum, sumsq of x1) accumulated in
// registers, shfl-reduced over the 16-lane col group, cross-wave via LDS,
// written as deterministic per-block partials. Deletes the full 134 MB
// ln_stats(x1) pass.
__global__ __launch_bounds__(256, 2) void gemm_pw2_kernel(
    const unsigned short* __restrict__ t, const float* __restrict__ x,
    const float* __restrict__ wf, const float* __restrict__ cf,
    float* __restrict__ x1, float* __restrict__ part_sum, float* __restrict__ part_sq) {
  __shared__ float red_s[4][64], red_q[4][64];
  int n = blockIdx.y;
  int lane = threadIdx.x & 63, wid = threadIdx.x >> 6;
  int col = lane & 15, quad = lane >> 4;
  short8 a[4][2];
  const float* wfn = wf + (size_t)n * 64 * 64;
  #pragma unroll
  for (int mt = 0; mt < 4; mt++)
    #pragma unroll
    for (int ks = 0; ks < 2; ks++) {
      const float* wp = wfn + (mt * 16 + col) * 64 + ks * 32 + quad * 8;
      short8 v;
      #pragma unroll
      for (int j = 0; j < 8; j++) v[j] = f2bf(wp[j]);
      a[mt][ks] = v;
    }
  float cb[4][4];
  #pragma unroll
  for (int mt = 0; mt < 4; mt++)
    #pragma unroll
    for (int r = 0; r < 4; r++) cb[mt][r] = cf[n * 64 + mt * 16 + quad * 4 + r];
  const unsigned short* tn = t + (size_t)n * 64 * HWP;
  const float* xn = x + (size_t)n * 64 * HWP;
  float* x1n = x1 + (size_t)n * 64 * HWP;
  int pxbase = blockIdx.x * 512 + wid * 16 + col;
  float sacc[4][4], qacc[4][4];
  #pragma unroll
  for (int mt = 0; mt < 4; mt++)
    #pragma unroll
    for (int r = 0; r < 4; r++) { sacc[mt][r] = 0.f; qacc[mt][r] = 0.f; }
  for (int tile = 0; tile < 8; tile++) {
    int p = pxbase + tile * 64;
    short8 b[2];
    #pragma unroll
    for (int ks = 0; ks < 2; ks++)
      #pragma unroll
      for (int j = 0; j < 8; j++)
        b[ks][j] = (short)tn[(size_t)(ks * 32 + quad * 8 + j) * HWP + p];
    f32x4 acc[4];
    #pragma unroll
    for (int mt = 0; mt < 4; mt++) {
      acc[mt] = (f32x4){0.f, 0.f, 0.f, 0.f};
      acc[mt] = __builtin_amdgcn_mfma_f32_16x16x32_bf16(a[mt][0], b[0], acc[mt], 0, 0, 0);
      acc[mt] = __builtin_amdgcn_mfma_f32_16x16x32_bf16(a[mt][1], b[1], acc[mt], 0, 0, 0);
    }
    #pragma unroll
    for (int mt = 0; mt < 4; mt++)
      #pragma unroll
      for (int r = 0; r < 4; r++) {
        size_t idx = (size_t)(mt * 16 + quad * 4 + r) * HWP + p;
        float v = xn[idx] + acc[mt][r] + cb[mt][r];
        x1n[idx] = v;
        sacc[mt][r] += v;
        qacc[mt][r] += v * v;
      }
  }
  // reduce sum/sumsq over the 16 col lanes (same channel set per quad group)
  #pragma unroll
  for (int mt = 0; mt < 4; mt++)
    #pragma unroll
    for (int r = 0; r < 4; r++) {
      float s = sacc[mt][r], q = qacc[mt][r];
      #pragma unroll
      for (int off = 1; off < 16; off <<= 1) {
        s += __shfl_xor(s, off);
        q += __shfl_xor(q, off);
      }
      if (col == 0) {
        int o = mt * 16 + quad * 4 + r;
        red_s[wid][o] = s; red_q[wid][o] = q;
      }
    }
  __syncthreads();
  if (threadIdx.x < 64) {
    int c = threadIdx.x;
    float s = red_s[0][c] + red_s[1][c] + red_s[2][c] + red_s[3][c];
    float q = red_q[0][c] + red_q[1][c] + red_q[2][c] + red_q[3][c];
    size_t pidx = ((size_t)n * 64 + c) * 128 + blockIdx.x;
    part_sum[pidx] = s;
    part_sq[pidx]  = q;
  }
}

// -------- LN2 finalize (from gemm_pw2 partials) + fold into pw3 ------------
// One block per n. Phase 1: 64 threads reduce 128 partials/plane -> a,b in
// LDS. Phase 2: 128 threads fold into w3f/c3f. Replaces ln_stats + fold.
__global__ __launch_bounds__(256) void ln2fold_kernel(
    const float* __restrict__ w, const float* __restrict__ pb,
    const float* __restrict__ ps, const float* __restrict__ pq,
    const float* __restrict__ lw, const float* __restrict__ lb,
    float* __restrict__ wf, float* __restrict__ cf) {
  __shared__ float aa[64], bb[64];
  int n = blockIdx.x;
  if (threadIdx.x < 64) {
    int c = threadIdx.x;
    const float* p1 = ps + ((size_t)n * 64 + c) * 128;
    const float* p2 = pq + ((size_t)n * 64 + c) * 128;
    float S = 0.f, S2 = 0.f;
    for (int k = 0; k < 128; k++) { S += p1[k]; S2 += p2[k]; }
    float mean = S * (1.f / (float)HWP);
    float var  = S2 * (1.f / (float)HWP) - mean * mean;
    float rstd = rsqrtf(var + 1e-6f);
    float av = rstd * lw[c];
    aa[c] = av;
    bb[c] = lb[c] - mean * av;
  }
  __syncthreads();
  if (threadIdx.x < 128) {
    int o = threadIdx.x;
    const float* wo = w + o * 64;
    float* wfo = wf + ((size_t)n * 128 + o) * 64;
    float cc = pb[o];
    for (int i = 0; i < 64; i++) { float wv = wo[i]; wfo[i] = wv * aa[i]; cc += wv * bb[i]; }
    cf[n * 128 + o] = cc;
  }
}

// -------- final via chained MFMA: out = x1 + b2*(W4 @ gate(W3' @ x1 + c3) + c4)
__global__ __launch_bounds__(256, 2) void final_mfma_kernel(
    const float* __restrict__ x1, const float* __restrict__ w3f,
    const float* __restrict__ c3f, const float* __restrict__ w4,
    const float* __restrict__ pb4, const float* __restrict__ beta2,
    float* __restrict__ out) {
  __shared__ float s_c3[128];
  __shared__ float s_b2[64];
  __shared__ float s_c4[64];
  __shared__ __align__(16) unsigned g_lds[64 * 33];  // [pixel][j/2], stride 33 dwords
  int n = blockIdx.y;
  int lane = threadIdx.x & 63, wid = threadIdx.x >> 6;
  int col = lane & 15, quad = lane >> 4;
  if (threadIdx.x < 128) s_c3[threadIdx.x] = c3f[n * 128 + threadIdx.x];
  if (threadIdx.x < 64) { s_b2[threadIdx.x] = beta2[threadIdx.x]; s_c4[threadIdx.x] = pb4[threadIdx.x]; }
  short8 a3[8][2];
  const float* wfn = w3f + (size_t)n * 128 * 64;
  #pragma unroll
  for (int mt = 0; mt < 8; mt++)
    #pragma unroll
    for (int ks = 0; ks < 2; ks++) {
      const float* wp = wfn + (mt * 16 + col) * 64 + ks * 32 + quad * 8;
      short8 v;
      #pragma unroll
      for (int j = 0; j < 8; j++) v[j] = f2bf(wp[j]);
      a3[mt][ks] = v;
    }
  short8 a4[4][2];
  #pragma unroll
  for (int mt = 0; mt < 4; mt++)
    #pragma unroll
    for (int ks = 0; ks < 2; ks++) {
      const float* wp = w4 + (mt * 16 + col) * 64 + ks * 32 + quad * 8;
      short8 v;
      #pragma unroll
      for (int j = 0; j < 8; j++) v[j] = f2bf(wp[j]);
      a4[mt][ks] = v;
    }
  __syncthreads();
  const float* x1n = x1 + (size_t)n * 64 * HWP;
  float* outn = out + (size_t)n * 64 * HWP;
  int pxbase = blockIdx.x * 512 + wid * 16 + col;
  unsigned* grow = g_lds + (wid * 16 + col) * 33;
  for (int tile = 0; tile < 8; tile++) {
    int p = pxbase + tile * 64;
    short8 b1[2];
    #pragma unroll
    for (int ks = 0; ks < 2; ks++)
      #pragma unroll
      for (int j = 0; j < 8; j++)
        b1[ks][j] = f2bf(x1n[(size_t)(ks * 32 + quad * 8 + j) * HWP + p]);
    f32x4 acc[8];
    #pragma unroll
    for (int mt = 0; mt < 8; mt++) {
      acc[mt] = (f32x4){0.f, 0.f, 0.f, 0.f};
      acc[mt] = __builtin_amdgcn_mfma_f32_16x16x32_bf16(a3[mt][0], b1[0], acc[mt], 0, 0, 0);
      acc[mt] = __builtin_amdgcn_mfma_f32_16x16x32_bf16(a3[mt][1], b1[1], acc[mt], 0, 0, 0);
    }
    #pragma unroll
    for (int mt = 0; mt < 4; mt++)
      #pragma unroll
      for (int rr = 0; rr < 2; rr++) {
        int j0 = mt * 16 + quad * 4 + rr * 2;
        float ga = (acc[mt][rr * 2]     + s_c3[j0])     * (acc[mt + 4][rr * 2]     + s_c3[64 + j0]);
        float gb = (acc[mt][rr * 2 + 1] + s_c3[j0 + 1]) * (acc[mt + 4][rr * 2 + 1] + s_c3[64 + j0 + 1]);
        unsigned lo = (unsigned short)f2bf(ga);
        unsigned hi = (unsigned short)f2bf(gb);
        grow[j0 >> 1] = lo | (hi << 16);
      }
    __syncthreads();
    short8 b2[2];
    #pragma unroll
    for (int ks = 0; ks < 2; ks++)
      #pragma unroll
      for (int w = 0; w < 4; w++) {
        unsigned u = grow[ks * 16 + quad * 4 + w];
        b2[ks][2 * w]     = (short)(u & 0xFFFFu);
        b2[ks][2 * w + 1] = (short)(u >> 16);
      }
    __syncthreads();
    f32x4 acc2[4];
    #pragma unroll
    for (int mt = 0; mt < 4; mt++) {
      acc2[mt] = (f32x4){0.f, 0.f, 0.f, 0.f};
      acc2[mt] = __builtin_amdgcn_mfma_f32_16x16x32_bf16(a4[mt][0], b2[0], acc2[mt], 0, 0, 0);
      acc2[mt] = __builtin_amdgcn_mfma_f32_16x16x32_bf16(a4[mt][1], b2[1], acc2[mt], 0, 0, 0);
    }
    #pragma unroll
    for (int mt = 0; mt < 4; mt++)
      #pragma unroll
      for (int r = 0; r < 4; r++) {
        int o = mt * 16 + quad * 4 + r;
        size_t idx = (size_t)o * HWP + p;
        outn[idx] = x1n[idx] + s_b2[o] * (acc2[mt][r] + s_c4[o]);
      }
  }
}

extern "C" void kernel_launch(void* const* d_in, const int* in_sizes, int n_in,
                              void* d_out, int out_size, void* d_ws, size_t ws_size,
                              hipStream_t stream) {
  const float* x    = (const float*)d_in[0];
  const float* ln1w = (const float*)d_in[1];
  const float* ln1b = (const float*)d_in[2];
  const float* pw1w = (const float*)d_in[3];
  const float* pw1b = (const float*)d_in[4];
  const float* dww  = (const float*)d_in[5];
  const float* dwb  = (const float*)d_in[6];
  const float* scaw = (const float*)d_in[7];
  const float* scab = (const float*)d_in[8];
  const float* pw2w = (const float*)d_in[9];
  const float* pw2b = (const float*)d_in[10];
  const float* ln2w = (const float*)d_in[11];
  const float* ln2b = (const float*)d_in[12];
  const float* pw3w = (const float*)d_in[13];
  const float* pw3b = (const float*)d_in[14];
  const float* pw4w = (const float*)d_in[15];
  const float* pw4b = (const float*)d_in[16];
  const float* beta1= (const float*)d_in[17];
  const float* beta2= (const float*)d_in[18];
  float* out = (float*)d_out;

  char* ws = (char*)d_ws;
  unsigned short* z  = (unsigned short*)ws;          // bf16 bits, 134 MB
  float*          x1 = (float*)ws;                    // reuses z region (z dead)
  unsigned short* t  = (unsigned short*)(ws + 134217728ull);  // bf16 bits, 67 MB
  float* sm = (float*)(ws + 134217728ull + 67108864ull);
  float* a1 = sm;               float* b1 = a1 + 512;
  float* w1f = b1 + 512;        float* c1f = w1f + 65536;
  float* pooled2 = c1f + 1024;  float* sca = pooled2 + 1024;
  float* w2f = sca + 512;       float* c2f = w2f + 32768;
  float* part_sq = c2f + 512;   float* w3f = part_sq + 65536;
  float* c3f = w3f + 65536;
  float* part_sum = w1f;        // w1f dead after gemm_pw1 (exactly 65536 floats)

  hipLaunchKernelGGL(ln_stats_kernel, dim3(512), dim3(256), 0, stream, x, ln1w, ln1b, a1, b1);
  hipLaunchKernelGGL(fold_kernel, dim3(4), dim3(256), 0, stream, pw1w, pw1b, a1, b1, w1f, c1f, 128);
  hipLaunchKernelGGL(gemm_pw1_kernel, dim3(128, 8), dim3(256), 0, stream, x, w1f, c1f, z);
  hipLaunchKernelGGL(dwgate_kernel, dim3(1024), dim3(256), 0, stream, z, dww, dwb, t, pooled2);
  hipLaunchKernelGGL(sca_kernel, dim3(2), dim3(256), 0, stream, pooled2, scaw, scab, sca);
  hipLaunchKernelGGL(fold_pw2_kernel, dim3(2), dim3(256), 0, stream, pw2w, pw2b, sca, beta1, w2f, c2f);
  hipLaunchKernelGGL(gemm_pw2_kernel, dim3(128, 8), dim3(256), 0, stream, t, x, w2f, c2f, x1,
                     part_sum, part_sq);
  hipLaunchKernelGGL(ln2fold_kernel, dim3(8), dim3(256), 0, stream,
                     pw3w, pw3b, part_sum, part_sq, ln2w, ln2b, w3f, c3f);
  hipLaunchKernelGGL(final_mfma_kernel, dim3(128, 8), dim3(256), 0, stream,
                     x1, w3f, c3f, pw4w, pw4b, beta2, out);
}

// Round 2
// 591.477 us; speedup vs baseline: 1.1016x; 1.1016x over previous
//
#include <hip/hip_runtime.h>
#include <hip/hip_bf16.h>

#define NB 8
#define CC 64
#define HWP 65536          // H*W

typedef __attribute__((ext_vector_type(8))) short short8;
typedef __attribute__((ext_vector_type(4))) float f32x4;

__device__ __forceinline__ short f2bf(float f) {
  union { float f; unsigned u; } v; v.f = f;
  return (short)((v.u + 0x7FFF + ((v.u >> 16) & 1)) >> 16);
}
__device__ __forceinline__ float bf2f(unsigned short u) {
  union { unsigned u; float f; } v; v.u = ((unsigned)u) << 16; return v.f;
}

// ---------------- LN stats: one block per (n,c) plane --------------------
__global__ __launch_bounds__(256) void ln_stats_kernel(
    const float* __restrict__ x, const float* __restrict__ lw,
    const float* __restrict__ lb, float* __restrict__ a, float* __restrict__ b) {
  int plane = blockIdx.x;            // n*64 + c
  int c = plane & 63;
  const float4* p4 = (const float4*)(x + (size_t)plane * HWP);
  float s = 0.f, s2 = 0.f;
  for (int i = threadIdx.x; i < HWP / 4; i += 256) {
    float4 v = p4[i];
    s  += v.x + v.y + v.z + v.w;
    s2 += v.x * v.x + v.y * v.y + v.z * v.z + v.w * v.w;
  }
  for (int off = 32; off; off >>= 1) {
    s  += __shfl_down(s, off);
    s2 += __shfl_down(s2, off);
  }
  __shared__ float ls[4], ls2[4];
  int wid = threadIdx.x >> 6, lid = threadIdx.x & 63;
  if (lid == 0) { ls[wid] = s; ls2[wid] = s2; }
  __syncthreads();
  if (threadIdx.x == 0) {
    float S  = ls[0] + ls[1] + ls[2] + ls[3];
    float S2 = ls2[0] + ls2[1] + ls2[2] + ls2[3];
    float mean = S * (1.f / (float)HWP);
    float var  = S2 * (1.f / (float)HWP) - mean * mean;
    float rstd = rsqrtf(var + 1e-6f);
    float av = rstd * lw[c];
    a[plane] = av;
    b[plane] = lb[c] - mean * av;
  }
}

// -------- fold LN into pw weights -----------------------------------------
__global__ void fold_kernel(const float* __restrict__ w, const float* __restrict__ pb,
                            const float* __restrict__ a, const float* __restrict__ b,
                            float* __restrict__ wf, float* __restrict__ cf, int O) {
  int idx = blockIdx.x * blockDim.x + threadIdx.x;   // n*O + o
  if (idx >= NB * O) return;
  int n = idx / O, o = idx - n * O;
  const float* an = a + n * 64;
  const float* bn = b + n * 64;
  const float* wo = w + o * 64;
  float* wfo = wf + (size_t)idx * 64;
  float cc = pb[o];
  for (int i = 0; i < 64; i++) { float wv = wo[i]; wfo[i] = wv * an[i]; cc += wv * bn[i]; }
  cf[idx] = cc;
}

// ---------------- pw1 via MFMA: z[n,o,p] = W1'[n] @ x[n] + c1', M=128 -----
// 2048 blocks (256 px each), fully-unrolled 4-tile loop with prefetch:
// the b-fragment channel-gather (16 scalar loads) for tile t+1 issues
// before tile t's MFMA+stores, so HBM latency overlaps compute/stores.
__global__ __launch_bounds__(256, 2) void gemm_pw1_kernel(
    const float* __restrict__ x, const float* __restrict__ wf,
    const float* __restrict__ cf, unsigned short* __restrict__ z) {
  int n = blockIdx.y;
  int lane = threadIdx.x & 63, wid = threadIdx.x >> 6;
  int col = lane & 15, quad = lane >> 4;
  short8 a[8][2];
  const float* wfn = wf + (size_t)n * 128 * 64;
  #pragma unroll
  for (int mt = 0; mt < 8; mt++)
    #pragma unroll
    for (int ks = 0; ks < 2; ks++) {
      const float* wp = wfn + (mt * 16 + col) * 64 + ks * 32 + quad * 8;
      short8 v;
      #pragma unroll
      for (int j = 0; j < 8; j++) v[j] = f2bf(wp[j]);
      a[mt][ks] = v;
    }
  float cb[8][4];
  #pragma unroll
  for (int mt = 0; mt < 8; mt++)
    #pragma unroll
    for (int r = 0; r < 4; r++) cb[mt][r] = cf[n * 128 + mt * 16 + quad * 4 + r];
  const float* xn = x + (size_t)n * 64 * HWP;
  unsigned short* zn = z + (size_t)n * 128 * HWP;
  int pxbase = blockIdx.x * 256 + wid * 16 + col;

  auto load_b = [&](int p, short8* bf) {
    #pragma unroll
    for (int ks = 0; ks < 2; ks++) {
      short8 v;
      #pragma unroll
      for (int j = 0; j < 8; j++)
        v[j] = f2bf(xn[(size_t)(ks * 32 + quad * 8 + j) * HWP + p]);
      bf[ks] = v;
    }
  };

  short8 bb[2][2];
  load_b(pxbase, bb[0]);
  #pragma unroll
  for (int tile = 0; tile < 4; tile++) {
    int cur = tile & 1, nxt = cur ^ 1;
    int p = pxbase + tile * 64;
    if (tile < 3) load_b(p + 64, bb[nxt]);
    f32x4 acc[8];
    #pragma unroll
    for (int mt = 0; mt < 8; mt++) {
      acc[mt] = (f32x4){0.f, 0.f, 0.f, 0.f};
      acc[mt] = __builtin_amdgcn_mfma_f32_16x16x32_bf16(a[mt][0], bb[cur][0], acc[mt], 0, 0, 0);
      acc[mt] = __builtin_amdgcn_mfma_f32_16x16x32_bf16(a[mt][1], bb[cur][1], acc[mt], 0, 0, 0);
    }
    #pragma unroll
    for (int mt = 0; mt < 8; mt++)
      #pragma unroll
      for (int r = 0; r < 4; r++)
        zn[(size_t)(mt * 16 + quad * 4 + r) * HWP + p] =
            (unsigned short)f2bf(acc[mt][r] + cb[mt][r]);
  }
}

// ---- depthwise 3x3 + SimpleGate + pool: row-streaming stencil ------------
__global__ __launch_bounds__(256) void dwgate_kernel(
    const unsigned short* __restrict__ z, const float* __restrict__ dww,
    const float* __restrict__ dwb, unsigned short* __restrict__ t,
    float* __restrict__ pooled2) {
  int blk = blockIdx.x;              // plane*2 + half
  int plane = blk >> 1, half = blk & 1;
  int n = plane >> 6, c = plane & 63;
  int lane = threadIdx.x & 63, wv = threadIdx.x >> 6;
  const unsigned short* z0 = z + ((size_t)n * 128 + c) * HWP;
  const unsigned short* z1 = z0 + (size_t)64 * HWP;
  unsigned short* tp = t + (size_t)plane * HWP;
  float w0[9], w1[9];
  #pragma unroll
  for (int k = 0; k < 9; k++) { w0[k] = dww[c * 9 + k]; w1[k] = dww[(c + 64) * 9 + k]; }
  float bias0 = dwb[c], bias1 = dwb[c + 64];
  int r0 = half * 128 + wv * 32;
  int colb = lane * 4;

  float fa[3][4], la[3], ra[3];      // z0: slots prev, cur, next
  float fb[3][4], lb_[3], rb[3];     // z1

  auto loadrow = [&](const unsigned short* base, int h, float* f, float& l, float& r) {
    if ((unsigned)h < 256u) {
      ushort4 u = *(const ushort4*)(base + h * 256 + colb);
      f[0] = bf2f(u.x); f[1] = bf2f(u.y); f[2] = bf2f(u.z); f[3] = bf2f(u.w);
    } else {
      f[0] = f[1] = f[2] = f[3] = 0.f;
    }
    float ll = __shfl_up(f[3], 1);
    float rr = __shfl_down(f[0], 1);
    l = (lane == 0) ? 0.f : ll;
    r = (lane == 63) ? 0.f : rr;
  };

  loadrow(z0, r0 - 1, fa[0], la[0], ra[0]);
  loadrow(z1, r0 - 1, fb[0], lb_[0], rb[0]);
  loadrow(z0, r0,     fa[1], la[1], ra[1]);
  loadrow(z1, r0,     fb[1], lb_[1], rb[1]);

  float lsum = 0.f;
  #pragma unroll 2
  for (int h = r0; h < r0 + 32; h++) {
    loadrow(z0, h + 1, fa[2], la[2], ra[2]);
    loadrow(z1, h + 1, fb[2], lb_[2], rb[2]);
    float o0[4] = {bias0, bias0, bias0, bias0};
    float o1[4] = {bias1, bias1, bias1, bias1};
    #pragma unroll
    for (int rr_ = 0; rr_ < 3; rr_++) {
      float wl0 = w0[rr_ * 3], wc0 = w0[rr_ * 3 + 1], wr0 = w0[rr_ * 3 + 2];
      float wl1 = w1[rr_ * 3], wc1 = w1[rr_ * 3 + 1], wr1 = w1[rr_ * 3 + 2];
      const float* f0 = fa[rr_]; const float* f1 = fb[rr_];
      float l0 = la[rr_], r0h = ra[rr_], l1 = lb_[rr_], r1h = rb[rr_];
      o0[0] += wl0 * l0    + wc0 * f0[0] + wr0 * f0[1];
      o0[1] += wl0 * f0[0] + wc0 * f0[1] + wr0 * f0[2];
      o0[2] += wl0 * f0[1] + wc0 * f0[2] + wr0 * f0[3];
      o0[3] += wl0 * f0[2] + wc0 * f0[3] + wr0 * r0h;
      o1[0] += wl1 * l1    + wc1 * f1[0] + wr1 * f1[1];
      o1[1] += wl1 * f1[0] + wc1 * f1[1] + wr1 * f1[2];
      o1[2] += wl1 * f1[1] + wc1 * f1[2] + wr1 * f1[3];
      o1[3] += wl1 * f1[2] + wc1 * f1[3] + wr1 * r1h;
    }
    float g0 = o0[0] * o1[0], g1 = o0[1] * o1[1];
    float g2 = o0[2] * o1[2], g3 = o0[3] * o1[3];
    uint2 pk;
    pk.x = (unsigned)(unsigned short)f2bf(g0) | ((unsigned)(unsigned short)f2bf(g1) << 16);
    pk.y = (unsigned)(unsigned short)f2bf(g2) | ((unsigned)(unsigned short)f2bf(g3) << 16);
    *(uint2*)(tp + (size_t)h * 256 + colb) = pk;
    lsum += (g0 + g1) + (g2 + g3);
    #pragma unroll
    for (int i = 0; i < 4; i++) { fa[0][i] = fa[1][i]; fa[1][i] = fa[2][i];
                                  fb[0][i] = fb[1][i]; fb[1][i] = fb[2][i]; }
    la[0] = la[1]; la[1] = la[2]; ra[0] = ra[1]; ra[1] = ra[2];
    lb_[0] = lb_[1]; lb_[1] = lb_[2]; rb[0] = rb[1]; rb[1] = rb[2];
  }
  for (int off = 32; off; off >>= 1) lsum += __shfl_down(lsum, off);
  __shared__ float ls[4];
  if (lane == 0) ls[wv] = lsum;
  __syncthreads();
  if (threadIdx.x == 0) pooled2[plane * 2 + half] = ls[0] + ls[1] + ls[2] + ls[3];
}

// ---------------- SCA ------------------------------------------------------
__global__ void sca_kernel(const float* __restrict__ pooled2, const float* __restrict__ sw,
                           const float* __restrict__ sb, float* __restrict__ sca) {
  int idx = blockIdx.x * blockDim.x + threadIdx.x;   // n*64 + o
  if (idx >= 512) return;
  int n = idx >> 6, o = idx & 63;
  float s = sb[o];
  const float* pm = pooled2 + n * 64 * 2;
  for (int i = 0; i < 64; i++)
    s += sw[o * 64 + i] * (pm[i * 2] + pm[i * 2 + 1]) * (1.f / 65536.f);
  sca[idx] = 1.f / (1.f + expf(-s));
}

// -------- fold SCA scale + beta1 into pw2 weights ---------------------------
__global__ void fold_pw2_kernel(const float* __restrict__ w, const float* __restrict__ pb,
                                const float* __restrict__ sca, const float* __restrict__ beta1,
                                float* __restrict__ wf, float* __restrict__ cf) {
  int idx = blockIdx.x * blockDim.x + threadIdx.x;   // n*64 + o
  if (idx >= 512) return;
  int n = idx >> 6, o = idx & 63;
  float bt = beta1[o];
  const float* sn = sca + n * 64;
  float* wfo = wf + (size_t)idx * 64;
  for (int i = 0; i < 64; i++) wfo[i] = bt * w[o * 64 + i] * sn[i];
  cf[idx] = bt * pb[o];
}

// ---------------- pw2 + residual via MFMA: x1 = x + W2' @ t + c2', M=64 ----
// 2048 blocks, 4 tiles each, prefetched t-frag + x residual; fused LN2
// partial stats written as deterministic per-block partials (256/plane).
__global__ __launch_bounds__(256, 2) void gemm_pw2_kernel(
    const unsigned short* __restrict__ t, const float* __restrict__ x,
    const float* __restrict__ wf, const float* __restrict__ cf,
    float* __restrict__ x1, float* __restrict__ part_sum, float* __restrict__ part_sq) {
  __shared__ float red_s[4][64], red_q[4][64];
  int n = blockIdx.y;
  int lane = threadIdx.x & 63, wid = threadIdx.x >> 6;
  int col = lane & 15, quad = lane >> 4;
  short8 a[4][2];
  const float* wfn = wf + (size_t)n * 64 * 64;
  #pragma unroll
  for (int mt = 0; mt < 4; mt++)
    #pragma unroll
    for (int ks = 0; ks < 2; ks++) {
      const float* wp = wfn + (mt * 16 + col) * 64 + ks * 32 + quad * 8;
      short8 v;
      #pragma unroll
      for (int j = 0; j < 8; j++) v[j] = f2bf(wp[j]);
      a[mt][ks] = v;
    }
  float cb[4][4];
  #pragma unroll
  for (int mt = 0; mt < 4; mt++)
    #pragma unroll
    for (int r = 0; r < 4; r++) cb[mt][r] = cf[n * 64 + mt * 16 + quad * 4 + r];
  const unsigned short* tn = t + (size_t)n * 64 * HWP;
  const float* xn = x + (size_t)n * 64 * HWP;
  float* x1n = x1 + (size_t)n * 64 * HWP;
  int pxbase = blockIdx.x * 256 + wid * 16 + col;

  auto load_t = [&](int p, short8* bf) {
    #pragma unroll
    for (int ks = 0; ks < 2; ks++) {
      short8 v;
      #pragma unroll
      for (int j = 0; j < 8; j++)
        v[j] = (short)tn[(size_t)(ks * 32 + quad * 8 + j) * HWP + p];
      bf[ks] = v;
    }
  };
  auto load_x = [&](int p, float (*xv)[4]) {
    #pragma unroll
    for (int mt = 0; mt < 4; mt++)
      #pragma unroll
      for (int r = 0; r < 4; r++)
        xv[mt][r] = xn[(size_t)(mt * 16 + quad * 4 + r) * HWP + p];
  };

  float sacc[4][4], qacc[4][4];
  #pragma unroll
  for (int mt = 0; mt < 4; mt++)
    #pragma unroll
    for (int r = 0; r < 4; r++) { sacc[mt][r] = 0.f; qacc[mt][r] = 0.f; }

  short8 bb[2][2];
  float xv[2][4][4];
  load_t(pxbase, bb[0]);
  load_x(pxbase, xv[0]);
  #pragma unroll
  for (int tile = 0; tile < 4; tile++) {
    int cur = tile & 1, nxt = cur ^ 1;
    int p = pxbase + tile * 64;
    if (tile < 3) { load_t(p + 64, bb[nxt]); load_x(p + 64, xv[nxt]); }
    f32x4 acc[4];
    #pragma unroll
    for (int mt = 0; mt < 4; mt++) {
      acc[mt] = (f32x4){0.f, 0.f, 0.f, 0.f};
      acc[mt] = __builtin_amdgcn_mfma_f32_16x16x32_bf16(a[mt][0], bb[cur][0], acc[mt], 0, 0, 0);
      acc[mt] = __builtin_amdgcn_mfma_f32_16x16x32_bf16(a[mt][1], bb[cur][1], acc[mt], 0, 0, 0);
    }
    #pragma unroll
    for (int mt = 0; mt < 4; mt++)
      #pragma unroll
      for (int r = 0; r < 4; r++) {
        size_t idx = (size_t)(mt * 16 + quad * 4 + r) * HWP + p;
        float v = xv[cur][mt][r] + acc[mt][r] + cb[mt][r];
        x1n[idx] = v;
        sacc[mt][r] += v;
        qacc[mt][r] += v * v;
      }
  }
  // reduce sum/sumsq over the 16 col lanes (same channel set per quad group)
  #pragma unroll
  for (int mt = 0; mt < 4; mt++)
    #pragma unroll
    for (int r = 0; r < 4; r++) {
      float s = sacc[mt][r], q = qacc[mt][r];
      #pragma unroll
      for (int off = 1; off < 16; off <<= 1) {
        s += __shfl_xor(s, off);
        q += __shfl_xor(q, off);
      }
      if (col == 0) {
        int o = mt * 16 + quad * 4 + r;
        red_s[wid][o] = s; red_q[wid][o] = q;
      }
    }
  __syncthreads();
  if (threadIdx.x < 64) {
    int c = threadIdx.x;
    float s = red_s[0][c] + red_s[1][c] + red_s[2][c] + red_s[3][c];
    float q = red_q[0][c] + red_q[1][c] + red_q[2][c] + red_q[3][c];
    size_t pidx = ((size_t)n * 64 + c) * 256 + blockIdx.x;
    part_sum[pidx] = s;
    part_sq[pidx]  = q;
  }
}

// -------- LN2 finalize (from gemm_pw2 partials) + fold into pw3 ------------
__global__ __launch_bounds__(256) void ln2fold_kernel(
    const float* __restrict__ w, const float* __restrict__ pb,
    const float* __restrict__ ps, const float* __restrict__ pq,
    const float* __restrict__ lw, const float* __restrict__ lb,
    float* __restrict__ wf, float* __restrict__ cf) {
  __shared__ float aa[64], bb[64];
  int n = blockIdx.x;
  if (threadIdx.x < 64) {
    int c = threadIdx.x;
    const float* p1 = ps + ((size_t)n * 64 + c) * 256;
    const float* p2 = pq + ((size_t)n * 64 + c) * 256;
    float S = 0.f, S2 = 0.f;
    for (int k = 0; k < 256; k++) { S += p1[k]; S2 += p2[k]; }
    float mean = S * (1.f / (float)HWP);
    float var  = S2 * (1.f / (float)HWP) - mean * mean;
    float rstd = rsqrtf(var + 1e-6f);
    float av = rstd * lw[c];
    aa[c] = av;
    bb[c] = lb[c] - mean * av;
  }
  __syncthreads();
  if (threadIdx.x < 128) {
    int o = threadIdx.x;
    const float* wo = w + o * 64;
    float* wfo = wf + ((size_t)n * 128 + o) * 64;
    float cc = pb[o];
    for (int i = 0; i < 64; i++) { float wv = wo[i]; wfo[i] = wv * aa[i]; cc += wv * bb[i]; }
    cf[n * 128 + o] = cc;
  }
}

// -------- final via chained MFMA: out = x1 + b2*(W4 @ gate(W3' @ x1 + c3) + c4)
__global__ __launch_bounds__(256, 2) void final_mfma_kernel(
    const float* __restrict__ x1, const float* __restrict__ w3f,
    const float* __restrict__ c3f, const float* __restrict__ w4,
    const float* __restrict__ pb4, const float* __restrict__ beta2,
    float* __restrict__ out) {
  __shared__ float s_c3[128];
  __shared__ float s_b2[64];
  __shared__ float s_c4[64];
  __shared__ __align__(16) unsigned g_lds[64 * 33];  // [pixel][j/2], stride 33 dwords
  int n = blockIdx.y;
  int lane = threadIdx.x & 63, wid = threadIdx.x >> 6;
  int col = lane & 15, quad = lane >> 4;
  if (threadIdx.x < 128) s_c3[threadIdx.x] = c3f[n * 128 + threadIdx.x];
  if (threadIdx.x < 64) { s_b2[threadIdx.x] = beta2[threadIdx.x]; s_c4[threadIdx.x] = pb4[threadIdx.x]; }
  short8 a3[8][2];
  const float* wfn = w3f + (size_t)n * 128 * 64;
  #pragma unroll
  for (int mt = 0; mt < 8; mt++)
    #pragma unroll
    for (int ks = 0; ks < 2; ks++) {
      const float* wp = wfn + (mt * 16 + col) * 64 + ks * 32 + quad * 8;
      short8 v;
      #pragma unroll
      for (int j = 0; j < 8; j++) v[j] = f2bf(wp[j]);
      a3[mt][ks] = v;
    }
  short8 a4[4][2];
  #pragma unroll
  for (int mt = 0; mt < 4; mt++)
    #pragma unroll
    for (int ks = 0; ks < 2; ks++) {
      const float* wp = w4 + (mt * 16 + col) * 64 + ks * 32 + quad * 8;
      short8 v;
      #pragma unroll
      for (int j = 0; j < 8; j++) v[j] = f2bf(wp[j]);
      a4[mt][ks] = v;
    }
  __syncthreads();
  const float* x1n = x1 + (size_t)n * 64 * HWP;
  float* outn = out + (size_t)n * 64 * HWP;
  int pxbase = blockIdx.x * 256 + wid * 16 + col;
  unsigned* grow = g_lds + (wid * 16 + col) * 33;

  auto load_b1 = [&](int p, short8* bf) {
    #pragma unroll
    for (int ks = 0; ks < 2; ks++) {
      short8 v;
      #pragma unroll
      for (int j = 0; j < 8; j++)
        v[j] = f2bf(x1n[(size_t)(ks * 32 + quad * 8 + j) * HWP + p]);
      bf[ks] = v;
    }
  };

  short8 bb1[2][2];
  load_b1(pxbase, bb1[0]);
  #pragma unroll
  for (int tile = 0; tile < 4; tile++) {
    int cur = tile & 1, nxt = cur ^ 1;
    int p = pxbase + tile * 64;
    if (tile < 3) load_b1(p + 64, bb1[nxt]);
    f32x4 acc[8];
    #pragma unroll
    for (int mt = 0; mt < 8; mt++) {
      acc[mt] = (f32x4){0.f, 0.f, 0.f, 0.f};
      acc[mt] = __builtin_amdgcn_mfma_f32_16x16x32_bf16(a3[mt][0], bb1[cur][0], acc[mt], 0, 0, 0);
      acc[mt] = __builtin_amdgcn_mfma_f32_16x16x32_bf16(a3[mt][1], bb1[cur][1], acc[mt], 0, 0, 0);
    }
    #pragma unroll
    for (int mt = 0; mt < 4; mt++)
      #pragma unroll
      for (int rr = 0; rr < 2; rr++) {
        int j0 = mt * 16 + quad * 4 + rr * 2;
        float ga = (acc[mt][rr * 2]     + s_c3[j0])     * (acc[mt + 4][rr * 2]     + s_c3[64 + j0]);
        float gb = (acc[mt][rr * 2 + 1] + s_c3[j0 + 1]) * (acc[mt + 4][rr * 2 + 1] + s_c3[64 + j0 + 1]);
        unsigned lo = (unsigned short)f2bf(ga);
        unsigned hi = (unsigned short)f2bf(gb);
        grow[j0 >> 1] = lo | (hi << 16);
      }
    __syncthreads();
    short8 b2[2];
    #pragma unroll
    for (int ks = 0; ks < 2; ks++)
      #pragma unroll
      for (int w = 0; w < 4; w++) {
        unsigned u = grow[ks * 16 + quad * 4 + w];
        b2[ks][2 * w]     = (short)(u & 0xFFFFu);
        b2[ks][2 * w + 1] = (short)(u >> 16);
      }
    __syncthreads();
    f32x4 acc2[4];
    #pragma unroll
    for (int mt = 0; mt < 4; mt++) {
      acc2[mt] = (f32x4){0.f, 0.f, 0.f, 0.f};
      acc2[mt] = __builtin_amdgcn_mfma_f32_16x16x32_bf16(a4[mt][0], b2[0], acc2[mt], 0, 0, 0);
      acc2[mt] = __builtin_amdgcn_mfma_f32_16x16x32_bf16(a4[mt][1], b2[1], acc2[mt], 0, 0, 0);
    }
    #pragma unroll
    for (int mt = 0; mt < 4; mt++)
      #pragma unroll
      for (int r = 0; r < 4; r++) {
        int o = mt * 16 + quad * 4 + r;
        size_t idx = (size_t)o * HWP + p;
        outn[idx] = x1n[idx] + s_b2[o] * (acc2[mt][r] + s_c4[o]);
      }
  }
}

extern "C" void kernel_launch(void* const* d_in, const int* in_sizes, int n_in,
                              void* d_out, int out_size, void* d_ws, size_t ws_size,
                              hipStream_t stream) {
  const float* x    = (const float*)d_in[0];
  const float* ln1w = (const float*)d_in[1];
  const float* ln1b = (const float*)d_in[2];
  const float* pw1w = (const float*)d_in[3];
  const float* pw1b = (const float*)d_in[4];
  const float* dww  = (const float*)d_in[5];
  const float* dwb  = (const float*)d_in[6];
  const float* scaw = (const float*)d_in[7];
  const float* scab = (const float*)d_in[8];
  const float* pw2w = (const float*)d_in[9];
  const float* pw2b = (const float*)d_in[10];
  const float* ln2w = (const float*)d_in[11];
  const float* ln2b = (const float*)d_in[12];
  const float* pw3w = (const float*)d_in[13];
  const float* pw3b = (const float*)d_in[14];
  const float* pw4w = (const float*)d_in[15];
  const float* pw4b = (const float*)d_in[16];
  const float* beta1= (const float*)d_in[17];
  const float* beta2= (const float*)d_in[18];
  float* out = (float*)d_out;

  char* ws = (char*)d_ws;
  unsigned short* z  = (unsigned short*)ws;          // bf16 bits, 134 MB
  float*          x1 = (float*)ws;                    // reuses z region (z dead)
  unsigned short* t  = (unsigned short*)(ws + 134217728ull);  // bf16 bits, 67 MB
  float* sm = (float*)(ws + 134217728ull + 67108864ull);
  float* a1 = sm;               float* b1 = a1 + 512;
  float* w1f = b1 + 512;        float* c1f = w1f + 65536;
  float* pooled2 = c1f + 1024;  float* sca = pooled2 + 1024;
  float* w2f = sca + 512;       float* c2f = w2f + 32768;
  float* w3f = c2f + 512;       float* c3f = w3f + 65536;
  // LN2 partials (8n x 64c x 256 blocks, 512KB each) live in d_out:
  // out is written only by final_mfma, which runs after ln2fold consumed
  // them — stream-ordered, no hazard.
  float* part_sum = (float*)d_out;
  float* part_sq  = part_sum + 131072;

  hipLaunchKernelGGL(ln_stats_kernel, dim3(512), dim3(256), 0, stream, x, ln1w, ln1b, a1, b1);
  hipLaunchKernelGGL(fold_kernel, dim3(4), dim3(256), 0, stream, pw1w, pw1b, a1, b1, w1f, c1f, 128);
  hipLaunchKernelGGL(gemm_pw1_kernel, dim3(256, 8), dim3(256), 0, stream, x, w1f, c1f, z);
  hipLaunchKernelGGL(dwgate_kernel, dim3(1024), dim3(256), 0, stream, z, dww, dwb, t, pooled2);
  hipLaunchKernelGGL(sca_kernel, dim3(2), dim3(256), 0, stream, pooled2, scaw, scab, sca);
  hipLaunchKernelGGL(fold_pw2_kernel, dim3(2), dim3(256), 0, stream, pw2w, pw2b, sca, beta1, w2f, c2f);
  hipLaunchKernelGGL(gemm_pw2_kernel, dim3(256, 8), dim3(256), 0, stream, t, x, w2f, c2f, x1,
                     part_sum, part_sq);
  hipLaunchKernelGGL(ln2fold_kernel, dim3(8), dim3(256), 0, stream,
                     pw3w, pw3b, part_sum, part_sq, ln2w, ln2b, w3f, c3f);
  hipLaunchKernelGGL(final_mfma_kernel, dim3(256, 8), dim3(256), 0, stream,
                     x1, w3f, c3f, pw4w, pw4b, beta2, out);
}

// Round 3
// 563.637 us; speedup vs baseline: 1.1560x; 1.0494x over previous
//
#include <hip/hip_runtime.h>
#include <hip/hip_bf16.h>

#define NB 8
#define HWP 65536          // H*W

typedef __attribute__((ext_vector_type(8))) short short8;
typedef __attribute__((ext_vector_type(4))) float f32x4;

__device__ __forceinline__ short f2bf(float f) {
  union { float f; unsigned u; } v; v.f = f;
  return (short)((v.u + 0x7FFF + ((v.u >> 16) & 1)) >> 16);
}
__device__ __forceinline__ float bf2f(unsigned short u) {
  union { unsigned u; float f; } v; v.u = ((unsigned)u) << 16; return v.f;
}

// ---------------- LN stats: one block per (n,c) plane, 512 threads --------
__global__ __launch_bounds__(512) void ln_stats_kernel(
    const float* __restrict__ x, const float* __restrict__ lw,
    const float* __restrict__ lb, float* __restrict__ a, float* __restrict__ b) {
  int plane = blockIdx.x;            // n*64 + c
  int c = plane & 63;
  const float4* p4 = (const float4*)(x + (size_t)plane * HWP);
  float s = 0.f, s2 = 0.f;
  for (int i = threadIdx.x; i < HWP / 4; i += 512) {
    float4 v = p4[i];
    s  += v.x + v.y + v.z + v.w;
    s2 += v.x * v.x + v.y * v.y + v.z * v.z + v.w * v.w;
  }
  for (int off = 32; off; off >>= 1) {
    s  += __shfl_down(s, off);
    s2 += __shfl_down(s2, off);
  }
  __shared__ float ls[8], ls2[8];
  int wid = threadIdx.x >> 6, lid = threadIdx.x & 63;
  if (lid == 0) { ls[wid] = s; ls2[wid] = s2; }
  __syncthreads();
  if (threadIdx.x == 0) {
    float S = 0.f, S2 = 0.f;
    for (int k = 0; k < 8; k++) { S += ls[k]; S2 += ls2[k]; }
    float mean = S * (1.f / (float)HWP);
    float var  = S2 * (1.f / (float)HWP) - mean * mean;
    float rstd = rsqrtf(var + 1e-6f);
    float av = rstd * lw[c];
    a[plane] = av;
    b[plane] = lb[c] - mean * av;
  }
}

// -------- fold LN into pw weights; emit bf16 in MFMA fragment layout ------
// frag layout: [n][mt][ks][col16][quad4][j8] so a lane's 8-channel fragment
// is one contiguous 16-B short8.
__global__ void fold_kernel(const float* __restrict__ w, const float* __restrict__ pb,
                            const float* __restrict__ a, const float* __restrict__ b,
                            unsigned short* __restrict__ wf16, float* __restrict__ cf, int O) {
  int idx = blockIdx.x * blockDim.x + threadIdx.x;   // n*O + o
  if (idx >= NB * O) return;
  int n = idx / O, o = idx - n * O;
  int MT = O >> 4;
  const float* an = a + n * 64;
  const float* bn = b + n * 64;
  const float* wo = w + o * 64;
  int mt = o >> 4, cl = o & 15;
  float cc = pb[o];
  for (int i = 0; i < 64; i++) {
    float wv = wo[i];
    float wf = wv * an[i];
    cc += wv * bn[i];
    int ks = i >> 5, quad = (i >> 3) & 3, j = i & 7;
    wf16[((((size_t)(n * MT + mt) * 2 + ks) * 16 + cl) * 4 + quad) * 8 + j] =
        (unsigned short)f2bf(wf);
  }
  cf[idx] = cc;
}

// ---------------- pw1 via MFMA: z[n,o,p] = W1'[n] @ x[n] + c1', M=128 -----
// 512x8 blocks (128 px), vector-loaded bf16 weight fragments, bias as MFMA
// C-in, 2-tile prefetch.
__global__ __launch_bounds__(256, 2) void gemm_pw1_kernel(
    const float* __restrict__ x, const unsigned short* __restrict__ wf16,
    const float* __restrict__ cf, unsigned short* __restrict__ z) {
  int n = blockIdx.y;
  int lane = threadIdx.x & 63, wid = threadIdx.x >> 6;
  int col = lane & 15, quad = lane >> 4;
  const short8* wv8 = (const short8*)wf16 + (size_t)n * 1024;
  short8 a[8][2];
  #pragma unroll
  for (int mt = 0; mt < 8; mt++)
    #pragma unroll
    for (int ks = 0; ks < 2; ks++)
      a[mt][ks] = wv8[((mt * 2 + ks) * 16 + col) * 4 + quad];
  f32x4 cb[8];
  #pragma unroll
  for (int mt = 0; mt < 8; mt++)
    cb[mt] = *(const f32x4*)(cf + n * 128 + mt * 16 + quad * 4);
  const float* xn = x + (size_t)n * 64 * HWP;
  unsigned short* zn = z + (size_t)n * 128 * HWP;
  int pxbase = blockIdx.x * 128 + wid * 16 + col;

  auto load_b = [&](int p, short8* bf) {
    #pragma unroll
    for (int ks = 0; ks < 2; ks++) {
      short8 v;
      #pragma unroll
      for (int j = 0; j < 8; j++)
        v[j] = f2bf(xn[(size_t)(ks * 32 + quad * 8 + j) * HWP + p]);
      bf[ks] = v;
    }
  };

  short8 bb[2][2];
  load_b(pxbase, bb[0]);
  #pragma unroll
  for (int tile = 0; tile < 2; tile++) {
    int cur = tile & 1, nxt = cur ^ 1;
    int p = pxbase + tile * 64;
    if (tile < 1) load_b(p + 64, bb[nxt]);
    f32x4 acc[8];
    #pragma unroll
    for (int mt = 0; mt < 8; mt++) {
      acc[mt] = cb[mt];
      acc[mt] = __builtin_amdgcn_mfma_f32_16x16x32_bf16(a[mt][0], bb[cur][0], acc[mt], 0, 0, 0);
      acc[mt] = __builtin_amdgcn_mfma_f32_16x16x32_bf16(a[mt][1], bb[cur][1], acc[mt], 0, 0, 0);
    }
    #pragma unroll
    for (int mt = 0; mt < 8; mt++)
      #pragma unroll
      for (int r = 0; r < 4; r++)
        zn[(size_t)(mt * 16 + quad * 4 + r) * HWP + p] =
            (unsigned short)f2bf(acc[mt][r]);
  }
}

// ---- depthwise 3x3 + SimpleGate + pool: row-streaming stencil ------------
// 2048 blocks: one block per (n,c,quarter-plane). 4 waves x 16-row bands.
__global__ __launch_bounds__(256) void dwgate_kernel(
    const unsigned short* __restrict__ z, const float* __restrict__ dww,
    const float* __restrict__ dwb, unsigned short* __restrict__ t,
    float* __restrict__ pooled4) {
  int blk = blockIdx.x;              // plane*4 + qtr
  int plane = blk >> 2, qtr = blk & 3;
  int n = plane >> 6, c = plane & 63;
  int lane = threadIdx.x & 63, wv = threadIdx.x >> 6;
  const unsigned short* z0 = z + ((size_t)n * 128 + c) * HWP;
  const unsigned short* z1 = z0 + (size_t)64 * HWP;
  unsigned short* tp = t + (size_t)plane * HWP;
  float w0[9], w1[9];
  #pragma unroll
  for (int k = 0; k < 9; k++) { w0[k] = dww[c * 9 + k]; w1[k] = dww[(c + 64) * 9 + k]; }
  float bias0 = dwb[c], bias1 = dwb[c + 64];
  int r0 = qtr * 64 + wv * 16;
  int colb = lane * 4;

  float fa[3][4], la[3], ra[3];      // z0: slots prev, cur, next
  float fb[3][4], lb_[3], rb[3];     // z1

  auto loadrow = [&](const unsigned short* base, int h, float* f, float& l, float& r) {
    if ((unsigned)h < 256u) {
      ushort4 u = *(const ushort4*)(base + h * 256 + colb);
      f[0] = bf2f(u.x); f[1] = bf2f(u.y); f[2] = bf2f(u.z); f[3] = bf2f(u.w);
    } else {
      f[0] = f[1] = f[2] = f[3] = 0.f;
    }
    float ll = __shfl_up(f[3], 1);
    float rr = __shfl_down(f[0], 1);
    l = (lane == 0) ? 0.f : ll;
    r = (lane == 63) ? 0.f : rr;
  };

  loadrow(z0, r0 - 1, fa[0], la[0], ra[0]);
  loadrow(z1, r0 - 1, fb[0], lb_[0], rb[0]);
  loadrow(z0, r0,     fa[1], la[1], ra[1]);
  loadrow(z1, r0,     fb[1], lb_[1], rb[1]);

  float lsum = 0.f;
  #pragma unroll 2
  for (int h = r0; h < r0 + 16; h++) {
    loadrow(z0, h + 1, fa[2], la[2], ra[2]);
    loadrow(z1, h + 1, fb[2], lb_[2], rb[2]);
    float o0[4] = {bias0, bias0, bias0, bias0};
    float o1[4] = {bias1, bias1, bias1, bias1};
    #pragma unroll
    for (int rr_ = 0; rr_ < 3; rr_++) {
      float wl0 = w0[rr_ * 3], wc0 = w0[rr_ * 3 + 1], wr0 = w0[rr_ * 3 + 2];
      float wl1 = w1[rr_ * 3], wc1 = w1[rr_ * 3 + 1], wr1 = w1[rr_ * 3 + 2];
      const float* f0 = fa[rr_]; const float* f1 = fb[rr_];
      float l0 = la[rr_], r0h = ra[rr_], l1 = lb_[rr_], r1h = rb[rr_];
      o0[0] += wl0 * l0    + wc0 * f0[0] + wr0 * f0[1];
      o0[1] += wl0 * f0[0] + wc0 * f0[1] + wr0 * f0[2];
      o0[2] += wl0 * f0[1] + wc0 * f0[2] + wr0 * f0[3];
      o0[3] += wl0 * f0[2] + wc0 * f0[3] + wr0 * r0h;
      o1[0] += wl1 * l1    + wc1 * f1[0] + wr1 * f1[1];
      o1[1] += wl1 * f1[0] + wc1 * f1[1] + wr1 * f1[2];
      o1[2] += wl1 * f1[1] + wc1 * f1[2] + wr1 * f1[3];
      o1[3] += wl1 * f1[2] + wc1 * f1[3] + wr1 * r1h;
    }
    float g0 = o0[0] * o1[0], g1 = o0[1] * o1[1];
    float g2 = o0[2] * o1[2], g3 = o0[3] * o1[3];
    uint2 pk;
    pk.x = (unsigned)(unsigned short)f2bf(g0) | ((unsigned)(unsigned short)f2bf(g1) << 16);
    pk.y = (unsigned)(unsigned short)f2bf(g2) | ((unsigned)(unsigned short)f2bf(g3) << 16);
    *(uint2*)(tp + (size_t)h * 256 + colb) = pk;
    lsum += (g0 + g1) + (g2 + g3);
    #pragma unroll
    for (int i = 0; i < 4; i++) { fa[0][i] = fa[1][i]; fa[1][i] = fa[2][i];
                                  fb[0][i] = fb[1][i]; fb[1][i] = fb[2][i]; }
    la[0] = la[1]; la[1] = la[2]; ra[0] = ra[1]; ra[1] = ra[2];
    lb_[0] = lb_[1]; lb_[1] = lb_[2]; rb[0] = rb[1]; rb[1] = rb[2];
  }
  for (int off = 32; off; off >>= 1) lsum += __shfl_down(lsum, off);
  __shared__ float ls[4];
  if (lane == 0) ls[wv] = lsum;
  __syncthreads();
  if (threadIdx.x == 0) pooled4[plane * 4 + qtr] = ls[0] + ls[1] + ls[2] + ls[3];
}

// ---------------- SCA ------------------------------------------------------
__global__ void sca_kernel(const float* __restrict__ pooled4, const float* __restrict__ sw,
                           const float* __restrict__ sb, float* __restrict__ sca) {
  int idx = blockIdx.x * blockDim.x + threadIdx.x;   // n*64 + o
  if (idx >= 512) return;
  int n = idx >> 6, o = idx & 63;
  float s = sb[o];
  const float* pm = pooled4 + n * 256;
  for (int i = 0; i < 64; i++)
    s += sw[o * 64 + i] * (pm[i * 4] + pm[i * 4 + 1] + pm[i * 4 + 2] + pm[i * 4 + 3]) *
         (1.f / 65536.f);
  sca[idx] = 1.f / (1.f + expf(-s));
}

// -------- fold SCA scale + beta1 into pw2 weights (bf16 frag layout) -------
__global__ void fold_pw2_kernel(const float* __restrict__ w, const float* __restrict__ pb,
                                const float* __restrict__ sca, const float* __restrict__ beta1,
                                unsigned short* __restrict__ wf16, float* __restrict__ cf) {
  int idx = blockIdx.x * blockDim.x + threadIdx.x;   // n*64 + o
  if (idx >= 512) return;
  int n = idx >> 6, o = idx & 63;
  float bt = beta1[o];
  const float* sn = sca + n * 64;
  int mt = o >> 4, cl = o & 15;
  for (int i = 0; i < 64; i++) {
    float wf = bt * w[o * 64 + i] * sn[i];
    int ks = i >> 5, quad = (i >> 3) & 3, j = i & 7;
    wf16[((((size_t)(n * 4 + mt) * 2 + ks) * 16 + cl) * 4 + quad) * 8 + j] =
        (unsigned short)f2bf(wf);
  }
  cf[idx] = bt * pb[o];
}

// -------- fold beta2 into pw4 weights (bf16 frag layout, no n dim) ---------
__global__ void fold4_kernel(const float* __restrict__ w4, const float* __restrict__ pb4,
                             const float* __restrict__ beta2,
                             unsigned short* __restrict__ wf16, float* __restrict__ cf) {
  int o = threadIdx.x;
  if (o >= 64) return;
  float bt = beta2[o];
  int mt = o >> 4, cl = o & 15;
  for (int i = 0; i < 64; i++) {
    int ks = i >> 5, quad = (i >> 3) & 3, j = i & 7;
    wf16[((((size_t)mt * 2 + ks) * 16 + cl) * 4 + quad) * 8 + j] =
        (unsigned short)f2bf(bt * w4[o * 64 + i]);
  }
  cf[o] = bt * pb4[o];
}

// ---------------- pw2 + residual via MFMA: x1 = x + W2' @ t + c2', M=64 ----
// 512x8 blocks, 2-tile prefetch, fused LN2 partial stats (512/plane).
__global__ __launch_bounds__(256, 2) void gemm_pw2_kernel(
    const unsigned short* __restrict__ t, const float* __restrict__ x,
    const unsigned short* __restrict__ wf16, const float* __restrict__ cf,
    float* __restrict__ x1, float* __restrict__ part_sum, float* __restrict__ part_sq) {
  __shared__ float red_s[4][64], red_q[4][64];
  int n = blockIdx.y;
  int lane = threadIdx.x & 63, wid = threadIdx.x >> 6;
  int col = lane & 15, quad = lane >> 4;
  const short8* wv8 = (const short8*)wf16 + (size_t)n * 512;
  short8 a[4][2];
  #pragma unroll
  for (int mt = 0; mt < 4; mt++)
    #pragma unroll
    for (int ks = 0; ks < 2; ks++)
      a[mt][ks] = wv8[((mt * 2 + ks) * 16 + col) * 4 + quad];
  f32x4 cb[4];
  #pragma unroll
  for (int mt = 0; mt < 4; mt++)
    cb[mt] = *(const f32x4*)(cf + n * 64 + mt * 16 + quad * 4);
  const unsigned short* tn = t + (size_t)n * 64 * HWP;
  const float* xn = x + (size_t)n * 64 * HWP;
  float* x1n = x1 + (size_t)n * 64 * HWP;
  int pxbase = blockIdx.x * 128 + wid * 16 + col;

  auto load_t = [&](int p, short8* bf) {
    #pragma unroll
    for (int ks = 0; ks < 2; ks++) {
      short8 v;
      #pragma unroll
      for (int j = 0; j < 8; j++)
        v[j] = (short)tn[(size_t)(ks * 32 + quad * 8 + j) * HWP + p];
      bf[ks] = v;
    }
  };
  auto load_x = [&](int p, float (*xv)[4]) {
    #pragma unroll
    for (int mt = 0; mt < 4; mt++)
      #pragma unroll
      for (int r = 0; r < 4; r++)
        xv[mt][r] = xn[(size_t)(mt * 16 + quad * 4 + r) * HWP + p];
  };

  float sacc[4][4], qacc[4][4];
  #pragma unroll
  for (int mt = 0; mt < 4; mt++)
    #pragma unroll
    for (int r = 0; r < 4; r++) { sacc[mt][r] = 0.f; qacc[mt][r] = 0.f; }

  short8 bb[2][2];
  float xv[2][4][4];
  load_t(pxbase, bb[0]);
  load_x(pxbase, xv[0]);
  #pragma unroll
  for (int tile = 0; tile < 2; tile++) {
    int cur = tile & 1, nxt = cur ^ 1;
    int p = pxbase + tile * 64;
    if (tile < 1) { load_t(p + 64, bb[nxt]); load_x(p + 64, xv[nxt]); }
    f32x4 acc[4];
    #pragma unroll
    for (int mt = 0; mt < 4; mt++) {
      acc[mt] = cb[mt];
      acc[mt] = __builtin_amdgcn_mfma_f32_16x16x32_bf16(a[mt][0], bb[cur][0], acc[mt], 0, 0, 0);
      acc[mt] = __builtin_amdgcn_mfma_f32_16x16x32_bf16(a[mt][1], bb[cur][1], acc[mt], 0, 0, 0);
    }
    #pragma unroll
    for (int mt = 0; mt < 4; mt++)
      #pragma unroll
      for (int r = 0; r < 4; r++) {
        size_t idx = (size_t)(mt * 16 + quad * 4 + r) * HWP + p;
        float v = xv[cur][mt][r] + acc[mt][r];
        x1n[idx] = v;
        sacc[mt][r] += v;
        qacc[mt][r] += v * v;
      }
  }
  #pragma unroll
  for (int mt = 0; mt < 4; mt++)
    #pragma unroll
    for (int r = 0; r < 4; r++) {
      float s = sacc[mt][r], q = qacc[mt][r];
      #pragma unroll
      for (int off = 1; off < 16; off <<= 1) {
        s += __shfl_xor(s, off);
        q += __shfl_xor(q, off);
      }
      if (col == 0) {
        int o = mt * 16 + quad * 4 + r;
        red_s[wid][o] = s; red_q[wid][o] = q;
      }
    }
  __syncthreads();
  if (threadIdx.x < 64) {
    int c = threadIdx.x;
    float s = red_s[0][c] + red_s[1][c] + red_s[2][c] + red_s[3][c];
    float q = red_q[0][c] + red_q[1][c] + red_q[2][c] + red_q[3][c];
    size_t pidx = ((size_t)n * 64 + c) * 512 + blockIdx.x;
    part_sum[pidx] = s;
    part_sq[pidx]  = q;
  }
}

// -------- LN2 finalize (from gemm_pw2 partials) + fold into pw3 ------------
__global__ __launch_bounds__(256) void ln2fold_kernel(
    const float* __restrict__ w, const float* __restrict__ pb,
    const float* __restrict__ ps, const float* __restrict__ pq,
    const float* __restrict__ lw, const float* __restrict__ lb,
    unsigned short* __restrict__ wf16, float* __restrict__ cf) {
  __shared__ float aa[64], bbv[64];
  int n = blockIdx.x;
  if (threadIdx.x < 64) {
    int c = threadIdx.x;
    const float* p1 = ps + ((size_t)n * 64 + c) * 512;
    const float* p2 = pq + ((size_t)n * 64 + c) * 512;
    float S = 0.f, S2 = 0.f;
    for (int k = 0; k < 512; k++) { S += p1[k]; S2 += p2[k]; }
    float mean = S * (1.f / (float)HWP);
    float var  = S2 * (1.f / (float)HWP) - mean * mean;
    float rstd = rsqrtf(var + 1e-6f);
    float av = rstd * lw[c];
    aa[c] = av;
    bbv[c] = lb[c] - mean * av;
  }
  __syncthreads();
  if (threadIdx.x < 128) {
    int o = threadIdx.x;
    const float* wo = w + o * 64;
    int mt = o >> 4, cl = o & 15;
    float cc = pb[o];
    for (int i = 0; i < 64; i++) {
      float wv = wo[i];
      float wf = wv * aa[i];
      cc += wv * bbv[i];
      int ks = i >> 5, quad = (i >> 3) & 3, j = i & 7;
      wf16[((((size_t)(n * 8 + mt) * 2 + ks) * 16 + cl) * 4 + quad) * 8 + j] =
          (unsigned short)f2bf(wf);
    }
    cf[n * 128 + o] = cc;
  }
}

// -------- final: out = x1 + (W4'' @ gate(W3' @ x1 + c3) + c4'')
// Barrier-free main loop: gate->b2 channel redistribution is intra-wave
// (same pixel => same col+wid), done with 16 shfl (ds_bpermute) per tile
// instead of an LDS roundtrip + 2 syncthreads.
__global__ __launch_bounds__(256, 2) void final_mfma_kernel(
    const float* __restrict__ x1, const unsigned short* __restrict__ w3f16,
    const float* __restrict__ c3f, const unsigned short* __restrict__ w4f16,
    const float* __restrict__ c4f, float* __restrict__ out) {
  __shared__ float s_c3[128];
  __shared__ __align__(16) float s_c4[64];
  int n = blockIdx.y;
  int lane = threadIdx.x & 63, wid = threadIdx.x >> 6;
  int col = lane & 15, quad = lane >> 4;
  if (threadIdx.x < 128) s_c3[threadIdx.x] = c3f[n * 128 + threadIdx.x];
  if (threadIdx.x < 64) s_c4[threadIdx.x] = c4f[threadIdx.x];
  const short8* w3v = (const short8*)w3f16 + (size_t)n * 1024;
  short8 a3[8][2];
  #pragma unroll
  for (int mt = 0; mt < 8; mt++)
    #pragma unroll
    for (int ks = 0; ks < 2; ks++)
      a3[mt][ks] = w3v[((mt * 2 + ks) * 16 + col) * 4 + quad];
  const short8* w4v = (const short8*)w4f16;
  short8 a4[4][2];
  #pragma unroll
  for (int mt = 0; mt < 4; mt++)
    #pragma unroll
    for (int ks = 0; ks < 2; ks++)
      a4[mt][ks] = w4v[((mt * 2 + ks) * 16 + col) * 4 + quad];
  __syncthreads();
  const float* x1n = x1 + (size_t)n * 64 * HWP;
  float* outn = out + (size_t)n * 64 * HWP;
  int pxbase = blockIdx.x * 128 + wid * 16 + col;

  auto load_b1 = [&](int p, short8* bf) {
    #pragma unroll
    for (int ks = 0; ks < 2; ks++) {
      short8 v;
      #pragma unroll
      for (int j = 0; j < 8; j++)
        v[j] = f2bf(x1n[(size_t)(ks * 32 + quad * 8 + j) * HWP + p]);
      bf[ks] = v;
    }
  };

  short8 bb1[2][2];
  load_b1(pxbase, bb1[0]);
  #pragma unroll
  for (int tile = 0; tile < 2; tile++) {
    int cur = tile & 1, nxt = cur ^ 1;
    int p = pxbase + tile * 64;
    if (tile < 1) load_b1(p + 64, bb1[nxt]);
    f32x4 acc[8];
    #pragma unroll
    for (int mt = 0; mt < 8; mt++) {
      acc[mt] = (f32x4){0.f, 0.f, 0.f, 0.f};
      acc[mt] = __builtin_amdgcn_mfma_f32_16x16x32_bf16(a3[mt][0], bb1[cur][0], acc[mt], 0, 0, 0);
      acc[mt] = __builtin_amdgcn_mfma_f32_16x16x32_bf16(a3[mt][1], bb1[cur][1], acc[mt], 0, 0, 0);
    }
    // gate + pack: lane holds channels mt*16+quad*4+r (r=0..3) as 8 dwords
    unsigned pd[4][2];
    #pragma unroll
    for (int mt = 0; mt < 4; mt++)
      #pragma unroll
      for (int u = 0; u < 2; u++) {
        int c0 = mt * 16 + quad * 4 + 2 * u;
        float ga = (acc[mt][2 * u]     + s_c3[c0])     * (acc[mt + 4][2 * u]     + s_c3[64 + c0]);
        float gb = (acc[mt][2 * u + 1] + s_c3[c0 + 1]) * (acc[mt + 4][2 * u + 1] + s_c3[64 + c0 + 1]);
        pd[mt][u] = (unsigned)(unsigned short)f2bf(ga) |
                    ((unsigned)(unsigned short)f2bf(gb) << 16);
      }
    // redistribute: b2[ks][j] = gate channel ks*32+quad*8+j of own pixel.
    // source lane = ((quad&1)*2 + (w>>1))*16 + col; register = pd[ks*2 + (quad>>1)][w&1]
    short8 b2f[2];
    #pragma unroll
    for (int ks = 0; ks < 2; ks++)
      #pragma unroll
      for (int w = 0; w < 4; w++) {
        int src = ((quad & 1) * 2 + (w >> 1)) * 16 + col;
        unsigned v0 = (unsigned)__shfl((int)pd[ks * 2][w & 1], src, 64);
        unsigned v1 = (unsigned)__shfl((int)pd[ks * 2 + 1][w & 1], src, 64);
        unsigned u = (quad & 2) ? v1 : v0;
        b2f[ks][2 * w]     = (short)(u & 0xFFFFu);
        b2f[ks][2 * w + 1] = (short)(u >> 16);
      }
    f32x4 acc2[4];
    #pragma unroll
    for (int mt = 0; mt < 4; mt++) {
      acc2[mt] = *(const f32x4*)&s_c4[mt * 16 + quad * 4];
      acc2[mt] = __builtin_amdgcn_mfma_f32_16x16x32_bf16(a4[mt][0], b2f[0], acc2[mt], 0, 0, 0);
      acc2[mt] = __builtin_amdgcn_mfma_f32_16x16x32_bf16(a4[mt][1], b2f[1], acc2[mt], 0, 0, 0);
    }
    #pragma unroll
    for (int mt = 0; mt < 4; mt++)
      #pragma unroll
      for (int r = 0; r < 4; r++) {
        size_t idx = (size_t)(mt * 16 + quad * 4 + r) * HWP + p;
        outn[idx] = x1n[idx] + acc2[mt][r];
      }
  }
}

extern "C" void kernel_launch(void* const* d_in, const int* in_sizes, int n_in,
                              void* d_out, int out_size, void* d_ws, size_t ws_size,
                              hipStream_t stream) {
  const float* x    = (const float*)d_in[0];
  const float* ln1w = (const float*)d_in[1];
  const float* ln1b = (const float*)d_in[2];
  const float* pw1w = (const float*)d_in[3];
  const float* pw1b = (const float*)d_in[4];
  const float* dww  = (const float*)d_in[5];
  const float* dwb  = (const float*)d_in[6];
  const float* scaw = (const float*)d_in[7];
  const float* scab = (const float*)d_in[8];
  const float* pw2w = (const float*)d_in[9];
  const float* pw2b = (const float*)d_in[10];
  const float* ln2w = (const float*)d_in[11];
  const float* ln2b = (const float*)d_in[12];
  const float* pw3w = (const float*)d_in[13];
  const float* pw3b = (const float*)d_in[14];
  const float* pw4w = (const float*)d_in[15];
  const float* pw4b = (const float*)d_in[16];
  const float* beta1= (const float*)d_in[17];
  const float* beta2= (const float*)d_in[18];
  float* out = (float*)d_out;

  char* ws = (char*)d_ws;
  unsigned short* z  = (unsigned short*)ws;          // bf16 bits, 134 MB
  float*          x1 = (float*)ws;                    // reuses z region (z dead)
  unsigned short* t  = (unsigned short*)(ws + 134217728ull);  // bf16 bits, 67 MB
  float* sm = (float*)(ws + 134217728ull + 67108864ull);
  float* a1 = sm;                   // 512
  float* b1 = a1 + 512;             // 512
  float* c1f = b1 + 512;            // 1024
  float* pooled4 = c1f + 1024;      // 2048
  float* sca = pooled4 + 2048;      // 512
  float* c2f = sca + 512;           // 512
  float* c3f = c2f + 512;           // 1024
  float* c4f = c3f + 1024;          // 64  (float offset 6208 -> 16B aligned)
  unsigned short* w1f16 = (unsigned short*)(c4f + 64);   // 65536 us
  unsigned short* w2f16 = w1f16 + 65536;                  // 32768 us
  unsigned short* w3f16 = w2f16 + 32768;                  // 65536 us
  unsigned short* w4f16 = w3f16 + 65536;                  // 4096 us
  // LN2 partials (8n x 64c x 512 blocks, 1MB each) live in d_out: out is
  // written only by final_mfma, after ln2fold consumed them (stream-ordered).
  float* part_sum = (float*)d_out;
  float* part_sq  = part_sum + 262144;

  hipLaunchKernelGGL(ln_stats_kernel, dim3(512), dim3(512), 0, stream, x, ln1w, ln1b, a1, b1);
  hipLaunchKernelGGL(fold_kernel, dim3(4), dim3(256), 0, stream, pw1w, pw1b, a1, b1, w1f16, c1f, 128);
  hipLaunchKernelGGL(fold4_kernel, dim3(1), dim3(64), 0, stream, pw4w, pw4b, beta2, w4f16, c4f);
  hipLaunchKernelGGL(gemm_pw1_kernel, dim3(512, 8), dim3(256), 0, stream, x, w1f16, c1f, z);
  hipLaunchKernelGGL(dwgate_kernel, dim3(2048), dim3(256), 0, stream, z, dww, dwb, t, pooled4);
  hipLaunchKernelGGL(sca_kernel, dim3(2), dim3(256), 0, stream, pooled4, scaw, scab, sca);
  hipLaunchKernelGGL(fold_pw2_kernel, dim3(2), dim3(256), 0, stream, pw2w, pw2b, sca, beta1, w2f16, c2f);
  hipLaunchKernelGGL(gemm_pw2_kernel, dim3(512, 8), dim3(256), 0, stream, t, x, w2f16, c2f, x1,
                     part_sum, part_sq);
  hipLaunchKernelGGL(ln2fold_kernel, dim3(8), dim3(256), 0, stream,
                     pw3w, pw3b, part_sum, part_sq, ln2w, ln2b, w3f16, c3f);
  hipLaunchKernelGGL(final_mfma_kernel, dim3(512, 8), dim3(256), 0, stream,
                     x1, w3f16, c3f, w4f16, c4f, out);
}

// Round 4
// 562.220 us; speedup vs baseline: 1.1589x; 1.0025x over previous
//
#include <hip/hip_runtime.h>
#include <hip/hip_bf16.h>

#define NB 8
#define HWP 65536          // H*W (input/output plane stride, fixed)
#define ZS  65664          // z plane stride, bf16 elems (+256B: breaks 2^18 camping)
#define TS  65664          // t plane stride, bf16 elems
#define XS  65600          // x1 plane stride, f32 elems (+256B)

typedef __attribute__((ext_vector_type(8))) short short8;
typedef __attribute__((ext_vector_type(4))) float f32x4;

__device__ __forceinline__ short f2bf(float f) {
  union { float f; unsigned u; } v; v.f = f;
  return (short)((v.u + 0x7FFF + ((v.u >> 16) & 1)) >> 16);
}
__device__ __forceinline__ float bf2f(unsigned short u) {
  union { unsigned u; float f; } v; v.u = ((unsigned)u) << 16; return v.f;
}

// ---------------- LN stats: one block per (n,c) plane, 512 threads --------
__global__ __launch_bounds__(512) void ln_stats_kernel(
    const float* __restrict__ x, const float* __restrict__ lw,
    const float* __restrict__ lb, float* __restrict__ a, float* __restrict__ b) {
  int plane = blockIdx.x;            // n*64 + c
  int c = plane & 63;
  const float4* p4 = (const float4*)(x + (size_t)plane * HWP);
  float s = 0.f, s2 = 0.f;
  for (int i = threadIdx.x; i < HWP / 4; i += 512) {
    float4 v = p4[i];
    s  += v.x + v.y + v.z + v.w;
    s2 += v.x * v.x + v.y * v.y + v.z * v.z + v.w * v.w;
  }
  for (int off = 32; off; off >>= 1) {
    s  += __shfl_down(s, off);
    s2 += __shfl_down(s2, off);
  }
  __shared__ float ls[8], ls2[8];
  int wid = threadIdx.x >> 6, lid = threadIdx.x & 63;
  if (lid == 0) { ls[wid] = s; ls2[wid] = s2; }
  __syncthreads();
  if (threadIdx.x == 0) {
    float S = 0.f, S2 = 0.f;
    for (int k = 0; k < 8; k++) { S += ls[k]; S2 += ls2[k]; }
    float mean = S * (1.f / (float)HWP);
    float var  = S2 * (1.f / (float)HWP) - mean * mean;
    float rstd = rsqrtf(var + 1e-6f);
    float av = rstd * lw[c];
    a[plane] = av;
    b[plane] = lb[c] - mean * av;
  }
}

// -------- fold LN into pw weights; emit bf16 in MFMA fragment layout ------
__global__ void fold_kernel(const float* __restrict__ w, const float* __restrict__ pb,
                            const float* __restrict__ a, const float* __restrict__ b,
                            unsigned short* __restrict__ wf16, float* __restrict__ cf, int O) {
  int idx = blockIdx.x * blockDim.x + threadIdx.x;   // n*O + o
  if (idx >= NB * O) return;
  int n = idx / O, o = idx - n * O;
  int MT = O >> 4;
  const float* an = a + n * 64;
  const float* bn = b + n * 64;
  const float* wo = w + o * 64;
  int mt = o >> 4, cl = o & 15;
  float cc = pb[o];
  for (int i = 0; i < 64; i++) {
    float wv = wo[i];
    float wf = wv * an[i];
    cc += wv * bn[i];
    int ks = i >> 5, quad = (i >> 3) & 3, j = i & 7;
    wf16[((((size_t)(n * MT + mt) * 2 + ks) * 16 + cl) * 4 + quad) * 8 + j] =
        (unsigned short)f2bf(wf);
  }
  cf[idx] = cc;
}

// -------- fold beta2 into pw4 weights (bf16 frag layout, no n dim) ---------
__global__ void fold4_kernel(const float* __restrict__ w4, const float* __restrict__ pb4,
                             const float* __restrict__ beta2,
                             unsigned short* __restrict__ wf16, float* __restrict__ cf) {
  int o = threadIdx.x;
  if (o >= 64) return;
  float bt = beta2[o];
  int mt = o >> 4, cl = o & 15;
  for (int i = 0; i < 64; i++) {
    int ks = i >> 5, quad = (i >> 3) & 3, j = i & 7;
    wf16[((((size_t)mt * 2 + ks) * 16 + cl) * 4 + quad) * 8 + j] =
        (unsigned short)f2bf(bt * w4[o * 64 + i]);
  }
  cf[o] = bt * pb4[o];
}

// ---------------- pw1 via MFMA: z[n,o,p] = W1'[n] @ x[n] + c1', M=128 -----
__global__ __launch_bounds__(256, 2) void gemm_pw1_kernel(
    const float* __restrict__ x, const unsigned short* __restrict__ wf16,
    const float* __restrict__ cf, unsigned short* __restrict__ z) {
  int n = blockIdx.y;
  int lane = threadIdx.x & 63, wid = threadIdx.x >> 6;
  int col = lane & 15, quad = lane >> 4;
  const short8* wv8 = (const short8*)wf16 + (size_t)n * 1024;
  short8 a[8][2];
  #pragma unroll
  for (int mt = 0; mt < 8; mt++)
    #pragma unroll
    for (int ks = 0; ks < 2; ks++)
      a[mt][ks] = wv8[((mt * 2 + ks) * 16 + col) * 4 + quad];
  f32x4 cb[8];
  #pragma unroll
  for (int mt = 0; mt < 8; mt++)
    cb[mt] = *(const f32x4*)(cf + n * 128 + mt * 16 + quad * 4);
  const float* xn = x + (size_t)n * 64 * HWP;
  unsigned short* zn = z + (size_t)n * 128 * ZS;
  int pxbase = blockIdx.x * 128 + wid * 16 + col;

  auto load_b = [&](int p, short8* bf) {
    #pragma unroll
    for (int ks = 0; ks < 2; ks++) {
      short8 v;
      #pragma unroll
      for (int j = 0; j < 8; j++)
        v[j] = f2bf(xn[(size_t)(ks * 32 + quad * 8 + j) * HWP + p]);
      bf[ks] = v;
    }
  };

  short8 bb[2][2];
  load_b(pxbase, bb[0]);
  #pragma unroll
  for (int tile = 0; tile < 2; tile++) {
    int cur = tile & 1, nxt = cur ^ 1;
    int p = pxbase + tile * 64;
    if (tile < 1) load_b(p + 64, bb[nxt]);
    f32x4 acc[8];
    #pragma unroll
    for (int mt = 0; mt < 8; mt++) {
      acc[mt] = cb[mt];
      acc[mt] = __builtin_amdgcn_mfma_f32_16x16x32_bf16(a[mt][0], bb[cur][0], acc[mt], 0, 0, 0);
      acc[mt] = __builtin_amdgcn_mfma_f32_16x16x32_bf16(a[mt][1], bb[cur][1], acc[mt], 0, 0, 0);
    }
    #pragma unroll
    for (int mt = 0; mt < 8; mt++)
      #pragma unroll
      for (int r = 0; r < 4; r++)
        zn[(size_t)(mt * 16 + quad * 4 + r) * ZS + p] =
            (unsigned short)f2bf(acc[mt][r]);
  }
}

// ---- depthwise 3x3 + SimpleGate + pool: row-streaming stencil ------------
__global__ __launch_bounds__(256) void dwgate_kernel(
    const unsigned short* __restrict__ z, const float* __restrict__ dww,
    const float* __restrict__ dwb, unsigned short* __restrict__ t,
    float* __restrict__ pooled4) {
  int blk = blockIdx.x;              // plane*4 + qtr
  int plane = blk >> 2, qtr = blk & 3;
  int n = plane >> 6, c = plane & 63;
  int lane = threadIdx.x & 63, wv = threadIdx.x >> 6;
  const unsigned short* z0 = z + ((size_t)n * 128 + c) * ZS;
  const unsigned short* z1 = z0 + (size_t)64 * ZS;
  unsigned short* tp = t + (size_t)plane * TS;
  float w0[9], w1[9];
  #pragma unroll
  for (int k = 0; k < 9; k++) { w0[k] = dww[c * 9 + k]; w1[k] = dww[(c + 64) * 9 + k]; }
  float bias0 = dwb[c], bias1 = dwb[c + 64];
  int r0 = qtr * 64 + wv * 16;
  int colb = lane * 4;

  float fa[3][4], la[3], ra[3];      // z0: slots prev, cur, next
  float fb[3][4], lb_[3], rb[3];     // z1

  auto loadrow = [&](const unsigned short* base, int h, float* f, float& l, float& r) {
    if ((unsigned)h < 256u) {
      ushort4 u = *(const ushort4*)(base + h * 256 + colb);
      f[0] = bf2f(u.x); f[1] = bf2f(u.y); f[2] = bf2f(u.z); f[3] = bf2f(u.w);
    } else {
      f[0] = f[1] = f[2] = f[3] = 0.f;
    }
    float ll = __shfl_up(f[3], 1);
    float rr = __shfl_down(f[0], 1);
    l = (lane == 0) ? 0.f : ll;
    r = (lane == 63) ? 0.f : rr;
  };

  loadrow(z0, r0 - 1, fa[0], la[0], ra[0]);
  loadrow(z1, r0 - 1, fb[0], lb_[0], rb[0]);
  loadrow(z0, r0,     fa[1], la[1], ra[1]);
  loadrow(z1, r0,     fb[1], lb_[1], rb[1]);

  float lsum = 0.f;
  #pragma unroll 2
  for (int h = r0; h < r0 + 16; h++) {
    loadrow(z0, h + 1, fa[2], la[2], ra[2]);
    loadrow(z1, h + 1, fb[2], lb_[2], rb[2]);
    float o0[4] = {bias0, bias0, bias0, bias0};
    float o1[4] = {bias1, bias1, bias1, bias1};
    #pragma unroll
    for (int rr_ = 0; rr_ < 3; rr_++) {
      float wl0 = w0[rr_ * 3], wc0 = w0[rr_ * 3 + 1], wr0 = w0[rr_ * 3 + 2];
      float wl1 = w1[rr_ * 3], wc1 = w1[rr_ * 3 + 1], wr1 = w1[rr_ * 3 + 2];
      const float* f0 = fa[rr_]; const float* f1 = fb[rr_];
      float l0 = la[rr_], r0h = ra[rr_], l1 = lb_[rr_], r1h = rb[rr_];
      o0[0] += wl0 * l0    + wc0 * f0[0] + wr0 * f0[1];
      o0[1] += wl0 * f0[0] + wc0 * f0[1] + wr0 * f0[2];
      o0[2] += wl0 * f0[1] + wc0 * f0[2] + wr0 * f0[3];
      o0[3] += wl0 * f0[2] + wc0 * f0[3] + wr0 * r0h;
      o1[0] += wl1 * l1    + wc1 * f1[0] + wr1 * f1[1];
      o1[1] += wl1 * f1[0] + wc1 * f1[1] + wr1 * f1[2];
      o1[2] += wl1 * f1[1] + wc1 * f1[2] + wr1 * f1[3];
      o1[3] += wl1 * f1[2] + wc1 * f1[3] + wr1 * r1h;
    }
    float g0 = o0[0] * o1[0], g1 = o0[1] * o1[1];
    float g2 = o0[2] * o1[2], g3 = o0[3] * o1[3];
    uint2 pk;
    pk.x = (unsigned)(unsigned short)f2bf(g0) | ((unsigned)(unsigned short)f2bf(g1) << 16);
    pk.y = (unsigned)(unsigned short)f2bf(g2) | ((unsigned)(unsigned short)f2bf(g3) << 16);
    *(uint2*)(tp + (size_t)h * 256 + colb) = pk;
    lsum += (g0 + g1) + (g2 + g3);
    #pragma unroll
    for (int i = 0; i < 4; i++) { fa[0][i] = fa[1][i]; fa[1][i] = fa[2][i];
                                  fb[0][i] = fb[1][i]; fb[1][i] = fb[2][i]; }
    la[0] = la[1]; la[1] = la[2]; ra[0] = ra[1]; ra[1] = ra[2];
    lb_[0] = lb_[1]; lb_[1] = lb_[2]; rb[0] = rb[1]; rb[1] = rb[2];
  }
  for (int off = 32; off; off >>= 1) lsum += __shfl_down(lsum, off);
  __shared__ float ls[4];
  if (lane == 0) ls[wv] = lsum;
  __syncthreads();
  if (threadIdx.x == 0) pooled4[plane * 4 + qtr] = ls[0] + ls[1] + ls[2] + ls[3];
}

// ------- SCA sigmoid + fold(beta1*sca) into pw2 weights, one kernel -------
// 2 blocks x 256 threads; block handles 4 n's (tid = ln*64 + o).
__global__ __launch_bounds__(256) void sca_fold_kernel(
    const float* __restrict__ pooled4, const float* __restrict__ sw,
    const float* __restrict__ sb, const float* __restrict__ w2,
    const float* __restrict__ pb2, const float* __restrict__ beta1,
    unsigned short* __restrict__ wf16, float* __restrict__ cf) {
  __shared__ float scal[4][64];
  int ln = threadIdx.x >> 6, o = threadIdx.x & 63;
  int n = blockIdx.x * 4 + ln;
  const float* pm = pooled4 + n * 256;
  float s = sb[o];
  for (int i = 0; i < 64; i++)
    s += sw[o * 64 + i] * (pm[i * 4] + pm[i * 4 + 1] + pm[i * 4 + 2] + pm[i * 4 + 3]) *
         (1.f / 65536.f);
  scal[ln][o] = 1.f / (1.f + expf(-s));
  __syncthreads();
  float bt = beta1[o];
  int mt = o >> 4, cl = o & 15;
  for (int i = 0; i < 64; i++) {
    float wf = bt * w2[o * 64 + i] * scal[ln][i];
    int ks = i >> 5, quad = (i >> 3) & 3, j = i & 7;
    wf16[((((size_t)(n * 4 + mt) * 2 + ks) * 16 + cl) * 4 + quad) * 8 + j] =
        (unsigned short)f2bf(wf);
  }
  cf[n * 64 + o] = bt * pb2[o];
}

// ---------------- pw2 + residual via MFMA: x1 = x + W2' @ t + c2', M=64 ----
__global__ __launch_bounds__(256, 2) void gemm_pw2_kernel(
    const unsigned short* __restrict__ t, const float* __restrict__ x,
    const unsigned short* __restrict__ wf16, const float* __restrict__ cf,
    float* __restrict__ x1, float* __restrict__ part_sum, float* __restrict__ part_sq) {
  __shared__ float red_s[4][64], red_q[4][64];
  int n = blockIdx.y;
  int lane = threadIdx.x & 63, wid = threadIdx.x >> 6;
  int col = lane & 15, quad = lane >> 4;
  const short8* wv8 = (const short8*)wf16 + (size_t)n * 512;
  short8 a[4][2];
  #pragma unroll
  for (int mt = 0; mt < 4; mt++)
    #pragma unroll
    for (int ks = 0; ks < 2; ks++)
      a[mt][ks] = wv8[((mt * 2 + ks) * 16 + col) * 4 + quad];
  f32x4 cb[4];
  #pragma unroll
  for (int mt = 0; mt < 4; mt++)
    cb[mt] = *(const f32x4*)(cf + n * 64 + mt * 16 + quad * 4);
  const unsigned short* tn = t + (size_t)n * 64 * TS;
  const float* xn = x + (size_t)n * 64 * HWP;
  float* x1n = x1 + (size_t)n * 64 * XS;
  int pxbase = blockIdx.x * 128 + wid * 16 + col;

  auto load_t = [&](int p, short8* bf) {
    #pragma unroll
    for (int ks = 0; ks < 2; ks++) {
      short8 v;
      #pragma unroll
      for (int j = 0; j < 8; j++)
        v[j] = (short)tn[(size_t)(ks * 32 + quad * 8 + j) * TS + p];
      bf[ks] = v;
    }
  };
  auto load_x = [&](int p, float (*xv)[4]) {
    #pragma unroll
    for (int mt = 0; mt < 4; mt++)
      #pragma unroll
      for (int r = 0; r < 4; r++)
        xv[mt][r] = xn[(size_t)(mt * 16 + quad * 4 + r) * HWP + p];
  };

  float sacc[4][4], qacc[4][4];
  #pragma unroll
  for (int mt = 0; mt < 4; mt++)
    #pragma unroll
    for (int r = 0; r < 4; r++) { sacc[mt][r] = 0.f; qacc[mt][r] = 0.f; }

  short8 bb[2][2];
  float xv[2][4][4];
  load_t(pxbase, bb[0]);
  load_x(pxbase, xv[0]);
  #pragma unroll
  for (int tile = 0; tile < 2; tile++) {
    int cur = tile & 1, nxt = cur ^ 1;
    int p = pxbase + tile * 64;
    if (tile < 1) { load_t(p + 64, bb[nxt]); load_x(p + 64, xv[nxt]); }
    f32x4 acc[4];
    #pragma unroll
    for (int mt = 0; mt < 4; mt++) {
      acc[mt] = cb[mt];
      acc[mt] = __builtin_amdgcn_mfma_f32_16x16x32_bf16(a[mt][0], bb[cur][0], acc[mt], 0, 0, 0);
      acc[mt] = __builtin_amdgcn_mfma_f32_16x16x32_bf16(a[mt][1], bb[cur][1], acc[mt], 0, 0, 0);
    }
    #pragma unroll
    for (int mt = 0; mt < 4; mt++)
      #pragma unroll
      for (int r = 0; r < 4; r++) {
        size_t idx = (size_t)(mt * 16 + quad * 4 + r) * XS + p;
        float v = xv[cur][mt][r] + acc[mt][r];
        x1n[idx] = v;
        sacc[mt][r] += v;
        qacc[mt][r] += v * v;
      }
  }
  #pragma unroll
  for (int mt = 0; mt < 4; mt++)
    #pragma unroll
    for (int r = 0; r < 4; r++) {
      float s = sacc[mt][r], q = qacc[mt][r];
      #pragma unroll
      for (int off = 1; off < 16; off <<= 1) {
        s += __shfl_xor(s, off);
        q += __shfl_xor(q, off);
      }
      if (col == 0) {
        int o = mt * 16 + quad * 4 + r;
        red_s[wid][o] = s; red_q[wid][o] = q;
      }
    }
  __syncthreads();
  if (threadIdx.x < 64) {
    int c = threadIdx.x;
    float s = red_s[0][c] + red_s[1][c] + red_s[2][c] + red_s[3][c];
    float q = red_q[0][c] + red_q[1][c] + red_q[2][c] + red_q[3][c];
    size_t pidx = ((size_t)n * 64 + c) * 512 + blockIdx.x;
    part_sum[pidx] = s;
    part_sq[pidx]  = q;
  }
}

// -------- LN2 finalize (from gemm_pw2 partials) + fold into pw3 ------------
// Phase 1: 256 threads = 64c x 4-way split of the 512 partials.
__global__ __launch_bounds__(256) void ln2fold_kernel(
    const float* __restrict__ w, const float* __restrict__ pb,
    const float* __restrict__ ps, const float* __restrict__ pq,
    const float* __restrict__ lw, const float* __restrict__ lb,
    unsigned short* __restrict__ wf16, float* __restrict__ cf) {
  __shared__ float aa[64], bbv[64];
  int n = blockIdx.x;
  int c = threadIdx.x >> 2, k4 = threadIdx.x & 3;
  const float* p1 = ps + ((size_t)n * 64 + c) * 512 + k4 * 128;
  const float* p2 = pq + ((size_t)n * 64 + c) * 512 + k4 * 128;
  float S = 0.f, S2 = 0.f;
  for (int k = 0; k < 128; k++) { S += p1[k]; S2 += p2[k]; }
  S  += __shfl_xor(S, 1);  S  += __shfl_xor(S, 2);
  S2 += __shfl_xor(S2, 1); S2 += __shfl_xor(S2, 2);
  if (k4 == 0) {
    float mean = S * (1.f / (float)HWP);
    float var  = S2 * (1.f / (float)HWP) - mean * mean;
    float rstd = rsqrtf(var + 1e-6f);
    float av = rstd * lw[c];
    aa[c] = av;
    bbv[c] = lb[c] - mean * av;
  }
  __syncthreads();
  if (threadIdx.x < 128) {
    int o = threadIdx.x;
    const float* wo = w + o * 64;
    int mt = o >> 4, cl = o & 15;
    float cc = pb[o];
    for (int i = 0; i < 64; i++) {
      float wv = wo[i];
      float wf = wv * aa[i];
      cc += wv * bbv[i];
      int ks = i >> 5, quad = (i >> 3) & 3, j = i & 7;
      wf16[((((size_t)(n * 8 + mt) * 2 + ks) * 16 + cl) * 4 + quad) * 8 + j] =
          (unsigned short)f2bf(wf);
    }
    cf[n * 128 + o] = cc;
  }
}

// -------- final: out = x1 + (W4'' @ gate(W3' @ x1 + c3) + c4'')
__global__ __launch_bounds__(256, 2) void final_mfma_kernel(
    const float* __restrict__ x1, const unsigned short* __restrict__ w3f16,
    const float* __restrict__ c3f, const unsigned short* __restrict__ w4f16,
    const float* __restrict__ c4f, float* __restrict__ out) {
  __shared__ float s_c3[128];
  __shared__ __align__(16) float s_c4[64];
  int n = blockIdx.y;
  int lane = threadIdx.x & 63, wid = threadIdx.x >> 6;
  int col = lane & 15, quad = lane >> 4;
  if (threadIdx.x < 128) s_c3[threadIdx.x] = c3f[n * 128 + threadIdx.x];
  if (threadIdx.x < 64) s_c4[threadIdx.x] = c4f[threadIdx.x];
  const short8* w3v = (const short8*)w3f16 + (size_t)n * 1024;
  short8 a3[8][2];
  #pragma unroll
  for (int mt = 0; mt < 8; mt++)
    #pragma unroll
    for (int ks = 0; ks < 2; ks++)
      a3[mt][ks] = w3v[((mt * 2 + ks) * 16 + col) * 4 + quad];
  const short8* w4v = (const short8*)w4f16;
  short8 a4[4][2];
  #pragma unroll
  for (int mt = 0; mt < 4; mt++)
    #pragma unroll
    for (int ks = 0; ks < 2; ks++)
      a4[mt][ks] = w4v[((mt * 2 + ks) * 16 + col) * 4 + quad];
  __syncthreads();
  const float* x1n = x1 + (size_t)n * 64 * XS;
  float* outn = out + (size_t)n * 64 * HWP;
  int pxbase = blockIdx.x * 128 + wid * 16 + col;

  auto load_b1 = [&](int p, short8* bf) {
    #pragma unroll
    for (int ks = 0; ks < 2; ks++) {
      short8 v;
      #pragma unroll
      for (int j = 0; j < 8; j++)
        v[j] = f2bf(x1n[(size_t)(ks * 32 + quad * 8 + j) * XS + p]);
      bf[ks] = v;
    }
  };

  short8 bb1[2][2];
  load_b1(pxbase, bb1[0]);
  #pragma unroll
  for (int tile = 0; tile < 2; tile++) {
    int cur = tile & 1, nxt = cur ^ 1;
    int p = pxbase + tile * 64;
    if (tile < 1) load_b1(p + 64, bb1[nxt]);
    f32x4 acc[8];
    #pragma unroll
    for (int mt = 0; mt < 8; mt++) {
      acc[mt] = (f32x4){0.f, 0.f, 0.f, 0.f};
      acc[mt] = __builtin_amdgcn_mfma_f32_16x16x32_bf16(a3[mt][0], bb1[cur][0], acc[mt], 0, 0, 0);
      acc[mt] = __builtin_amdgcn_mfma_f32_16x16x32_bf16(a3[mt][1], bb1[cur][1], acc[mt], 0, 0, 0);
    }
    unsigned pd[4][2];
    #pragma unroll
    for (int mt = 0; mt < 4; mt++)
      #pragma unroll
      for (int u = 0; u < 2; u++) {
        int c0 = mt * 16 + quad * 4 + 2 * u;
        float ga = (acc[mt][2 * u]     + s_c3[c0])     * (acc[mt + 4][2 * u]     + s_c3[64 + c0]);
        float gb = (acc[mt][2 * u + 1] + s_c3[c0 + 1]) * (acc[mt + 4][2 * u + 1] + s_c3[64 + c0 + 1]);
        pd[mt][u] = (unsigned)(unsigned short)f2bf(ga) |
                    ((unsigned)(unsigned short)f2bf(gb) << 16);
      }
    short8 b2f[2];
    #pragma unroll
    for (int ks = 0; ks < 2; ks++)
      #pragma unroll
      for (int w = 0; w < 4; w++) {
        int src = ((quad & 1) * 2 + (w >> 1)) * 16 + col;
        unsigned v0 = (unsigned)__shfl((int)pd[ks * 2][w & 1], src, 64);
        unsigned v1 = (unsigned)__shfl((int)pd[ks * 2 + 1][w & 1], src, 64);
        unsigned u = (quad & 2) ? v1 : v0;
        b2f[ks][2 * w]     = (short)(u & 0xFFFFu);
        b2f[ks][2 * w + 1] = (short)(u >> 16);
      }
    f32x4 acc2[4];
    #pragma unroll
    for (int mt = 0; mt < 4; mt++) {
      acc2[mt] = *(const f32x4*)&s_c4[mt * 16 + quad * 4];
      acc2[mt] = __builtin_amdgcn_mfma_f32_16x16x32_bf16(a4[mt][0], b2f[0], acc2[mt], 0, 0, 0);
      acc2[mt] = __builtin_amdgcn_mfma_f32_16x16x32_bf16(a4[mt][1], b2f[1], acc2[mt], 0, 0, 0);
    }
    #pragma unroll
    for (int mt = 0; mt < 4; mt++)
      #pragma unroll
      for (int r = 0; r < 4; r++) {
        size_t idx = (size_t)(mt * 16 + quad * 4 + r) * XS + p;
        outn[(size_t)(mt * 16 + quad * 4 + r) * HWP + p] = x1n[idx] + acc2[mt][r];
      }
  }
}

extern "C" void kernel_launch(void* const* d_in, const int* in_sizes, int n_in,
                              void* d_out, int out_size, void* d_ws, size_t ws_size,
                              hipStream_t stream) {
  const float* x    = (const float*)d_in[0];
  const float* ln1w = (const float*)d_in[1];
  const float* ln1b = (const float*)d_in[2];
  const float* pw1w = (const float*)d_in[3];
  const float* pw1b = (const float*)d_in[4];
  const float* dww  = (const float*)d_in[5];
  const float* dwb  = (const float*)d_in[6];
  const float* scaw = (const float*)d_in[7];
  const float* scab = (const float*)d_in[8];
  const float* pw2w = (const float*)d_in[9];
  const float* pw2b = (const float*)d_in[10];
  const float* ln2w = (const float*)d_in[11];
  const float* ln2b = (const float*)d_in[12];
  const float* pw3w = (const float*)d_in[13];
  const float* pw3b = (const float*)d_in[14];
  const float* pw4w = (const float*)d_in[15];
  const float* pw4b = (const float*)d_in[16];
  const float* beta1= (const float*)d_in[17];
  const float* beta2= (const float*)d_in[18];
  float* out = (float*)d_out;

  char* ws = (char*)d_ws;
  // z: 8n x 128ch x ZS bf16 = 134,479,872 B. x1 (reuses z region, z dead):
  // 8n x 64ch x XS f32 = 134,348,800 B. t: 8n x 64ch x TS bf16 = 67,239,936 B.
  unsigned short* z  = (unsigned short*)ws;
  float*          x1 = (float*)ws;
  unsigned short* t  = (unsigned short*)(ws + 134479872ull);
  float* sm = (float*)(ws + 134479872ull + 67239936ull);   // 16B aligned
  float* a1 = sm;                   // 512
  float* b1 = a1 + 512;             // 512
  float* c1f = b1 + 512;            // 1024
  float* pooled4 = c1f + 1024;      // 2048
  float* c2f = pooled4 + 2048;      // 512
  float* c3f = c2f + 512;           // 1024
  float* c4f = c3f + 1024;          // 64
  unsigned short* w1f16 = (unsigned short*)(c4f + 64);   // 65536 us
  unsigned short* w2f16 = w1f16 + 65536;                  // 32768 us
  unsigned short* w3f16 = w2f16 + 32768;                  // 65536 us
  unsigned short* w4f16 = w3f16 + 65536;                  // 4096 us
  // LN2 partials (8n x 64c x 512 blocks, 1MB each) live in d_out: out is
  // written only by final_mfma, after ln2fold consumed them (stream-ordered).
  float* part_sum = (float*)d_out;
  float* part_sq  = part_sum + 262144;

  hipLaunchKernelGGL(ln_stats_kernel, dim3(512), dim3(512), 0, stream, x, ln1w, ln1b, a1, b1);
  hipLaunchKernelGGL(fold_kernel, dim3(4), dim3(256), 0, stream, pw1w, pw1b, a1, b1, w1f16, c1f, 128);
  hipLaunchKernelGGL(fold4_kernel, dim3(1), dim3(64), 0, stream, pw4w, pw4b, beta2, w4f16, c4f);
  hipLaunchKernelGGL(gemm_pw1_kernel, dim3(512, 8), dim3(256), 0, stream, x, w1f16, c1f, z);
  hipLaunchKernelGGL(dwgate_kernel, dim3(2048), dim3(256), 0, stream, z, dww, dwb, t, pooled4);
  hipLaunchKernelGGL(sca_fold_kernel, dim3(2), dim3(256), 0, stream,
                     pooled4, scaw, scab, pw2w, pw2b, beta1, w2f16, c2f);
  hipLaunchKernelGGL(gemm_pw2_kernel, dim3(512, 8), dim3(256), 0, stream, t, x, w2f16, c2f, x1,
                     part_sum, part_sq);
  hipLaunchKernelGGL(ln2fold_kernel, dim3(8), dim3(256), 0, stream,
                     pw3w, pw3b, part_sum, part_sq, ln2w, ln2b, w3f16, c3f);
  hipLaunchKernelGGL(final_mfma_kernel, dim3(512, 8), dim3(256), 0, stream,
                     x1, w3f16, c3f, w4f16, c4f, out);
}